// Round 1
// baseline (478.569 us; speedup 1.0000x reference)
//
#include <hip/hip_runtime.h>
#include <math.h>

// Problem constants
static constexpr int NN  = 8192;     // nodes
static constexpr int EE  = 262144;   // edges
static constexpr int IND = 512;      // input feature dim
static constexpr int HH1 = 256;
static constexpr int HH2 = 64;

// ---------------- CSR build ----------------

__global__ void k_zero_counts(int* counts) {
    int i = blockIdx.x * 256 + threadIdx.x;
    if (i < NN) counts[i] = 0;
}

__global__ void k_hist(const int* __restrict__ erow, int* counts) {
    int e = blockIdx.x * 256 + threadIdx.x;
    if (e < EE) atomicAdd(&counts[erow[e]], 1);
}

// single-block exclusive scan of 8192 counts -> row_start[0..8192], cursor copy
__global__ __launch_bounds__(1024) void k_scan(const int* __restrict__ counts,
                                               int* row_start, int* cursor) {
    __shared__ int part[1024];
    int t = threadIdx.x;
    int base = t * 8;
    int loc[8];
    int s = 0;
#pragma unroll
    for (int i = 0; i < 8; i++) { loc[i] = s; s += counts[base + i]; }
    part[t] = s;
    __syncthreads();
    for (int off = 1; off < 1024; off <<= 1) {
        int v = (t >= off) ? part[t - off] : 0;
        __syncthreads();
        part[t] += v;
        __syncthreads();
    }
    int pre = (t > 0) ? part[t - 1] : 0;
#pragma unroll
    for (int i = 0; i < 8; i++) {
        int v = pre + loc[i];
        row_start[base + i] = v;
        cursor[base + i] = v;
    }
    if (t == 1023) row_start[NN] = part[1023];
}

__global__ void k_scatter(const int* __restrict__ erow, int* cursor, int* perm) {
    int e = blockIdx.x * 256 + threadIdx.x;
    if (e < EE) {
        int r = erow[e];
        int pos = atomicAdd(&cursor[r], 1);
        perm[pos] = e;
    }
}

// ---------------- GEMM 1: support1 = X @ W1  [8192,512]x[512,256] ----------------
__global__ __launch_bounds__(256) void k_gemm1(const float* __restrict__ X,
                                               const float* __restrict__ W,
                                               float* __restrict__ out) {
    __shared__ float Xs[16][IND];
    int row0 = blockIdx.x * 16;
    int c = threadIdx.x;
    for (int idx = c; idx < 16 * IND; idx += 256) {
        Xs[idx >> 9][idx & 511] = X[(size_t)row0 * IND + idx];
    }
    __syncthreads();
    float acc[16];
#pragma unroll
    for (int r = 0; r < 16; r++) acc[r] = 0.f;
    for (int k = 0; k < IND; k++) {
        float w = W[k * HH1 + c];
#pragma unroll
        for (int r = 0; r < 16; r++) acc[r] += Xs[r][k] * w;
    }
#pragma unroll
    for (int r = 0; r < 16; r++) out[(size_t)(row0 + r) * HH1 + c] = acc[r];
}

// ---------------- SpMM 1: h = tanh(A @ support1 + b1) ----------------
__global__ __launch_bounds__(256) void k_spmm1(const int* __restrict__ row_start,
                                               const int* __restrict__ perm,
                                               const int* __restrict__ ecol,
                                               const float* __restrict__ eval,
                                               const float* __restrict__ sup,
                                               const float* __restrict__ b1,
                                               float* __restrict__ h) {
    int row = blockIdx.x;
    int d = threadIdx.x;
    int s = row_start[row], eend = row_start[row + 1];
    float acc = 0.f;
    for (int i = s; i < eend; i++) {
        int e = perm[i];
        float v = eval[e];
        int col = ecol[e];
        acc += v * sup[(size_t)col * HH1 + d];
    }
    h[(size_t)row * HH1 + d] = tanhf(acc + b1[d]);
}

// ---------------- GEMM 2+3 fused: s23 = h @ [W2 | W3]  [8192,256]x[256,128] ----------------
__global__ __launch_bounds__(128) void k_gemm23(const float* __restrict__ h,
                                                const float* __restrict__ W2,
                                                const float* __restrict__ W3,
                                                float* __restrict__ s23) {
    __shared__ float hs[16 * HH1];
    int row0 = blockIdx.x * 16;
    int c = threadIdx.x;
    for (int idx = c; idx < 16 * HH1; idx += 128) {
        hs[idx] = h[(size_t)row0 * HH1 + idx];
    }
    __syncthreads();
    const float* Wp = (c < 64) ? W2 : W3;
    int cc = c & 63;
    float acc[16];
#pragma unroll
    for (int r = 0; r < 16; r++) acc[r] = 0.f;
    for (int k = 0; k < HH1; k++) {
        float w = Wp[k * 64 + cc];
#pragma unroll
        for (int r = 0; r < 16; r++) acc[r] += hs[r * HH1 + k] * w;
    }
#pragma unroll
    for (int r = 0; r < 16; r++) s23[(size_t)(row0 + r) * 128 + c] = acc[r];
}

// ---------------- SpMM 2+3 fused + reparameterization: z ----------------
__global__ __launch_bounds__(128) void k_spmm23(const int* __restrict__ row_start,
                                                const int* __restrict__ perm,
                                                const int* __restrict__ ecol,
                                                const float* __restrict__ eval,
                                                const float* __restrict__ s23,
                                                const float* __restrict__ b2,
                                                const float* __restrict__ b3,
                                                const float* __restrict__ noise,
                                                float* __restrict__ zout) {
    int row = blockIdx.x;
    int d = threadIdx.x;
    int s = row_start[row], eend = row_start[row + 1];
    float acc = 0.f;
    for (int i = s; i < eend; i++) {
        int e = perm[i];
        acc += eval[e] * s23[(size_t)ecol[e] * 128 + d];
    }
    float biased = acc + ((d < 64) ? b2[d] : b3[d - 64]);
    float t = tanhf(biased);
    __shared__ float sm[128];
    sm[d] = t;
    __syncthreads();
    if (d < 64) {
        zout[(size_t)row * 64 + d] = sm[d] + noise[(size_t)row * 64 + d] * expf(sm[d + 64]);
    }
}

// ---------------- adj = sigmoid(z @ z^T) ----------------
__global__ __launch_bounds__(256) void k_zzt(const float* __restrict__ z,
                                             float* __restrict__ adj) {
    // stride 68 floats: keeps float4 (16B) alignment, spreads banks
    __shared__ float zi[64 * 68];
    __shared__ float zj[64 * 68];
    int bi = blockIdx.y, bj = blockIdx.x;
    int tid = threadIdx.x;
    for (int idx = tid; idx < 64 * 64; idx += 256) {
        int r = idx >> 6, k = idx & 63;
        zi[r * 68 + k] = z[(size_t)(bi * 64 + r) * 64 + k];
        zj[r * 68 + k] = z[(size_t)(bj * 64 + r) * 64 + k];
    }
    __syncthreads();
    int tx = tid & 15, ty = tid >> 4;
    float acc[4][4] = {};
    const float* zip = &zi[(ty * 4) * 68];
    const float* zjp = &zj[(tx * 4) * 68];
    for (int k = 0; k < 64; k += 4) {
        float a[4][4], b[4][4];
#pragma unroll
        for (int r = 0; r < 4; r++) {
            float4 t4 = *(const float4*)&zip[r * 68 + k];
            a[r][0] = t4.x; a[r][1] = t4.y; a[r][2] = t4.z; a[r][3] = t4.w;
            float4 u4 = *(const float4*)&zjp[r * 68 + k];
            b[r][0] = u4.x; b[r][1] = u4.y; b[r][2] = u4.z; b[r][3] = u4.w;
        }
#pragma unroll
        for (int kk = 0; kk < 4; kk++) {
#pragma unroll
            for (int r = 0; r < 4; r++) {
#pragma unroll
                for (int cidx = 0; cidx < 4; cidx++) {
                    acc[r][cidx] += a[r][kk] * b[cidx][kk];
                }
            }
        }
    }
    size_t i0 = (size_t)bi * 64 + ty * 4;
    size_t j0 = (size_t)bj * 64 + tx * 4;
#pragma unroll
    for (int r = 0; r < 4; r++) {
        float4 o;
        o.x = 1.f / (1.f + expf(-acc[r][0]));
        o.y = 1.f / (1.f + expf(-acc[r][1]));
        o.z = 1.f / (1.f + expf(-acc[r][2]));
        o.w = 1.f / (1.f + expf(-acc[r][3]));
        *(float4*)&adj[(i0 + r) * NN + j0] = o;
    }
}

extern "C" void kernel_launch(void* const* d_in, const int* in_sizes, int n_in,
                              void* d_out, int out_size, void* d_ws, size_t ws_size,
                              hipStream_t stream) {
    const int*   erow  = (const int*)d_in[0];
    const int*   ecol  = (const int*)d_in[1];
    const float* eval  = (const float*)d_in[2];
    const float* X     = (const float*)d_in[3];
    const float* W1    = (const float*)d_in[4];
    const float* b1    = (const float*)d_in[5];
    const float* W2    = (const float*)d_in[6];
    const float* b2    = (const float*)d_in[7];
    const float* W3    = (const float*)d_in[8];
    const float* b3    = (const float*)d_in[9];
    const float* noise = (const float*)d_in[10];

    float* adj  = (float*)d_out;
    float* zout = (float*)d_out + (size_t)NN * NN;

    char* ws = (char*)d_ws;
    int*   counts    = (int*)(ws + 0);          // 8192 ints   -> 32768 B
    int*   row_start = (int*)(ws + 32768);      // 8193 ints   -> 32772 B
    int*   cursor    = (int*)(ws + 65792);      // 8192 ints
    int*   perm      = (int*)(ws + 98560);      // 262144 ints -> 1 MiB
    float* sup1      = (float*)(ws + 1147136);  // 8192*256 f32 -> 8 MiB
    float* h         = (float*)(ws + 9535744);  // 8192*256 f32 -> 8 MiB
    float* s23       = (float*)(ws + 17924352); // 8192*128 f32 -> 4 MiB
    // total ws usage: ~22.1 MB

    k_zero_counts<<<32, 256, 0, stream>>>(counts);
    k_hist<<<EE / 256, 256, 0, stream>>>(erow, counts);
    k_scan<<<1, 1024, 0, stream>>>(counts, row_start, cursor);
    k_scatter<<<EE / 256, 256, 0, stream>>>(erow, cursor, perm);

    k_gemm1<<<NN / 16, 256, 0, stream>>>(X, W1, sup1);
    k_spmm1<<<NN, 256, 0, stream>>>(row_start, perm, ecol, eval, sup1, b1, h);
    k_gemm23<<<NN / 16, 128, 0, stream>>>(h, W2, W3, s23);
    k_spmm23<<<NN, 128, 0, stream>>>(row_start, perm, ecol, eval, s23, b2, b3, noise, zout);
    k_zzt<<<dim3(128, 128), 256, 0, stream>>>(zout, adj);
}

// Round 2
// 289.440 us; speedup vs baseline: 1.6534x; 1.6534x over previous
//
#include <hip/hip_runtime.h>
#include <math.h>

// Problem constants
static constexpr int NN  = 8192;     // nodes
static constexpr int EE  = 262144;   // edges
static constexpr int IND = 512;      // input feature dim
static constexpr int HH1 = 256;
static constexpr int HH2 = 64;

typedef short bf16x8 __attribute__((ext_vector_type(8)));
typedef float f32x4  __attribute__((ext_vector_type(4)));

static __device__ __forceinline__ unsigned short f2bf(float f) {
    unsigned int u = __float_as_uint(f);
    u += 0x7fffu + ((u >> 16) & 1u);   // round-to-nearest-even
    return (unsigned short)(u >> 16);
}

// ---------------- CSR build ----------------

__global__ void k_zero_counts(int* counts) {
    int i = blockIdx.x * 256 + threadIdx.x;
    if (i < NN) counts[i] = 0;
}

__global__ void k_hist(const int* __restrict__ erow, int* counts) {
    int e = blockIdx.x * 256 + threadIdx.x;
    if (e < EE) atomicAdd(&counts[erow[e]], 1);
}

__global__ __launch_bounds__(1024) void k_scan(const int* __restrict__ counts,
                                               int* row_start, int* cursor) {
    __shared__ int part[1024];
    int t = threadIdx.x;
    int base = t * 8;
    int loc[8];
    int s = 0;
#pragma unroll
    for (int i = 0; i < 8; i++) { loc[i] = s; s += counts[base + i]; }
    part[t] = s;
    __syncthreads();
    for (int off = 1; off < 1024; off <<= 1) {
        int v = (t >= off) ? part[t - off] : 0;
        __syncthreads();
        part[t] += v;
        __syncthreads();
    }
    int pre = (t > 0) ? part[t - 1] : 0;
#pragma unroll
    for (int i = 0; i < 8; i++) {
        int v = pre + loc[i];
        row_start[base + i] = v;
        cursor[base + i] = v;
    }
    if (t == 1023) row_start[NN] = part[1023];
}

__global__ void k_scatter(const int* __restrict__ erow, int* cursor, int* perm) {
    int e = blockIdx.x * 256 + threadIdx.x;
    if (e < EE) {
        int r = erow[e];
        int pos = atomicAdd(&cursor[r], 1);
        perm[pos] = e;
    }
}

// ---------------- GEMM 1: support1 = X @ W1  [8192,512]x[512,256] ----------------
__global__ __launch_bounds__(256) void k_gemm1(const float* __restrict__ X,
                                               const float* __restrict__ W,
                                               float* __restrict__ out) {
    __shared__ float Xs[16][IND];
    int row0 = blockIdx.x * 16;
    int c = threadIdx.x;
    for (int idx = c; idx < 16 * IND; idx += 256) {
        Xs[idx >> 9][idx & 511] = X[(size_t)row0 * IND + idx];
    }
    __syncthreads();
    float acc[16];
#pragma unroll
    for (int r = 0; r < 16; r++) acc[r] = 0.f;
    for (int k = 0; k < IND; k += 4) {
        float w0 = W[(k + 0) * HH1 + c];
        float w1 = W[(k + 1) * HH1 + c];
        float w2 = W[(k + 2) * HH1 + c];
        float w3 = W[(k + 3) * HH1 + c];
#pragma unroll
        for (int r = 0; r < 16; r++) {
            float4 x = *(const float4*)&Xs[r][k];
            acc[r] += x.x * w0 + x.y * w1 + x.z * w2 + x.w * w3;
        }
    }
#pragma unroll
    for (int r = 0; r < 16; r++) out[(size_t)(row0 + r) * HH1 + c] = acc[r];
}

// ---------------- SpMM 1: h = tanh(A @ support1 + b1), wave per row, float4 ----------------
__global__ __launch_bounds__(256) void k_spmm1v(const int* __restrict__ row_start,
                                                const int* __restrict__ perm,
                                                const int* __restrict__ ecol,
                                                const float* __restrict__ eval,
                                                const float* __restrict__ sup,
                                                const float* __restrict__ b1,
                                                float* __restrict__ h) {
    int w = threadIdx.x >> 6, l = threadIdx.x & 63;
    int row = blockIdx.x * 4 + w;
    int s = row_start[row], eend = row_start[row + 1];
    const float4* supv = (const float4*)sup;   // each sup row = 64 float4
    float4 acc = make_float4(0.f, 0.f, 0.f, 0.f);
    for (int i = s; i < eend; i++) {
        int e = perm[i];
        float v = eval[e];
        int col = ecol[e];
        float4 t = supv[(size_t)col * 64 + l];
        acc.x += v * t.x; acc.y += v * t.y; acc.z += v * t.z; acc.w += v * t.w;
    }
    float4 bb = ((const float4*)b1)[l];
    float4 o;
    o.x = tanhf(acc.x + bb.x);
    o.y = tanhf(acc.y + bb.y);
    o.z = tanhf(acc.z + bb.z);
    o.w = tanhf(acc.w + bb.w);
    ((float4*)h)[(size_t)row * 64 + l] = o;
}

// ---------------- GEMM 2+3 fused: s23 = h @ [W2 | W3]  [8192,256]x[256,128] ----------------
__global__ __launch_bounds__(128) void k_gemm23(const float* __restrict__ h,
                                                const float* __restrict__ W2,
                                                const float* __restrict__ W3,
                                                float* __restrict__ s23) {
    __shared__ float hs[16 * HH1];
    int row0 = blockIdx.x * 16;
    int c = threadIdx.x;
    for (int idx = c; idx < 16 * HH1; idx += 128) {
        hs[idx] = h[(size_t)row0 * HH1 + idx];
    }
    __syncthreads();
    const float* Wp = (c < 64) ? W2 : W3;
    int cc = c & 63;
    float acc[16];
#pragma unroll
    for (int r = 0; r < 16; r++) acc[r] = 0.f;
    for (int k = 0; k < HH1; k += 4) {
        float w0 = Wp[(k + 0) * 64 + cc];
        float w1 = Wp[(k + 1) * 64 + cc];
        float w2 = Wp[(k + 2) * 64 + cc];
        float w3 = Wp[(k + 3) * 64 + cc];
#pragma unroll
        for (int r = 0; r < 16; r++) {
            float4 x = *(const float4*)&hs[r * HH1 + k];
            acc[r] += x.x * w0 + x.y * w1 + x.z * w2 + x.w * w3;
        }
    }
#pragma unroll
    for (int r = 0; r < 16; r++) s23[(size_t)(row0 + r) * 128 + c] = acc[r];
}

// ---------------- SpMM 2+3 fused + reparameterization, wave per row ----------------
__global__ __launch_bounds__(256) void k_spmm23v(const int* __restrict__ row_start,
                                                 const int* __restrict__ perm,
                                                 const int* __restrict__ ecol,
                                                 const float* __restrict__ eval,
                                                 const float* __restrict__ s23,
                                                 const float* __restrict__ b2,
                                                 const float* __restrict__ b3,
                                                 const float* __restrict__ noise,
                                                 float* __restrict__ zout,
                                                 unsigned short* __restrict__ zb) {
    int w = threadIdx.x >> 6, l = threadIdx.x & 63;
    int row = blockIdx.x * 4 + w;
    int s = row_start[row], eend = row_start[row + 1];
    const float2* sv = (const float2*)s23;   // each s23 row = 64 float2
    float2 acc = make_float2(0.f, 0.f);
    for (int i = s; i < eend; i++) {
        int e = perm[i];
        float v = eval[e];
        int col = ecol[e];
        float2 t = sv[(size_t)col * 64 + l];
        acc.x += v * t.x; acc.y += v * t.y;
    }
    float bx, by;
    if (l < 32) { bx = b2[2 * l]; by = b2[2 * l + 1]; }
    else        { bx = b3[2 * (l - 32)]; by = b3[2 * (l - 32) + 1]; }
    float t0 = tanhf(acc.x + bx);
    float t1 = tanhf(acc.y + by);
    float u0 = __shfl_xor(t0, 32, 64);   // mean lanes get log_std partner
    float u1 = __shfl_xor(t1, 32, 64);
    if (l < 32) {
        float2 nz = ((const float2*)noise)[(size_t)row * 32 + l];
        float z0 = t0 + nz.x * expf(u0);
        float z1 = t1 + nz.y * expf(u1);
        ((float2*)zout)[(size_t)row * 32 + l] = make_float2(z0, z1);
        unsigned int p = (unsigned int)f2bf(z0) | ((unsigned int)f2bf(z1) << 16);
        ((unsigned int*)zb)[(size_t)row * 32 + l] = p;
    }
}

// ---------------- adj = sigmoid(z @ z^T) via MFMA bf16, no LDS ----------------
// z bf16 is 1 MB -> L2-resident; load fragments straight from global.
// mfma_f32_16x16x32_bf16: A/B frag: row/col = lane&15, k = (lane>>4)*8 + i
//                         C/D:      col = lane&15,     row = (lane>>4)*4 + reg
__global__ __launch_bounds__(256) void k_zzt_mfma(const unsigned short* __restrict__ zb,
                                                  float* __restrict__ adj) {
    int bi = blockIdx.y, bj = blockIdx.x;
    int tid = threadIdx.x;
    int w = tid >> 6, l = tid & 63;
    int lr = l & 15, kg = l >> 4;
    const int i0 = bi * 128 + w * 32;   // this wave's 32 output rows
    const int j0 = bj * 128;

    bf16x8 a[2][2];
#pragma unroll
    for (int mt = 0; mt < 2; mt++)
#pragma unroll
        for (int kk = 0; kk < 2; kk++)
            a[mt][kk] = *(const bf16x8*)&zb[(size_t)(i0 + mt * 16 + lr) * 64 + kk * 32 + kg * 8];

    f32x4 acc[2][8];
#pragma unroll
    for (int mt = 0; mt < 2; mt++)
#pragma unroll
        for (int nt = 0; nt < 8; nt++)
            acc[mt][nt] = (f32x4){0.f, 0.f, 0.f, 0.f};

#pragma unroll
    for (int nt = 0; nt < 8; nt++) {
        bf16x8 b0 = *(const bf16x8*)&zb[(size_t)(j0 + nt * 16 + lr) * 64 + 0  + kg * 8];
        bf16x8 b1 = *(const bf16x8*)&zb[(size_t)(j0 + nt * 16 + lr) * 64 + 32 + kg * 8];
        acc[0][nt] = __builtin_amdgcn_mfma_f32_16x16x32_bf16(a[0][0], b0, acc[0][nt], 0, 0, 0);
        acc[0][nt] = __builtin_amdgcn_mfma_f32_16x16x32_bf16(a[0][1], b1, acc[0][nt], 0, 0, 0);
        acc[1][nt] = __builtin_amdgcn_mfma_f32_16x16x32_bf16(a[1][0], b0, acc[1][nt], 0, 0, 0);
        acc[1][nt] = __builtin_amdgcn_mfma_f32_16x16x32_bf16(a[1][1], b1, acc[1][nt], 0, 0, 0);
    }

#pragma unroll
    for (int mt = 0; mt < 2; mt++) {
#pragma unroll
        for (int nt = 0; nt < 8; nt++) {
            size_t rbase = (size_t)(i0 + mt * 16 + kg * 4);
            size_t col = (size_t)(j0 + nt * 16 + lr);
#pragma unroll
            for (int r = 0; r < 4; r++) {
                float v = acc[mt][nt][r];
                adj[(rbase + r) * NN + col] = 1.f / (1.f + expf(-v));
            }
        }
    }
}

extern "C" void kernel_launch(void* const* d_in, const int* in_sizes, int n_in,
                              void* d_out, int out_size, void* d_ws, size_t ws_size,
                              hipStream_t stream) {
    const int*   erow  = (const int*)d_in[0];
    const int*   ecol  = (const int*)d_in[1];
    const float* eval  = (const float*)d_in[2];
    const float* X     = (const float*)d_in[3];
    const float* W1    = (const float*)d_in[4];
    const float* b1    = (const float*)d_in[5];
    const float* W2    = (const float*)d_in[6];
    const float* b2    = (const float*)d_in[7];
    const float* W3    = (const float*)d_in[8];
    const float* b3    = (const float*)d_in[9];
    const float* noise = (const float*)d_in[10];

    float* adj  = (float*)d_out;
    float* zout = (float*)d_out + (size_t)NN * NN;

    char* ws = (char*)d_ws;
    int*   counts    = (int*)(ws + 0);          // 8192 ints
    int*   row_start = (int*)(ws + 32768);      // 8193 ints
    int*   cursor    = (int*)(ws + 65792);      // 8192 ints
    int*   perm      = (int*)(ws + 98560);      // 262144 ints -> 1 MiB
    float* sup1      = (float*)(ws + 1147136);  // 8192*256 f32 -> 8 MiB
    float* h         = (float*)(ws + 9535744);  // 8192*256 f32 -> 8 MiB
    float* s23       = (float*)(ws + 17924352); // 8192*128 f32 -> 4 MiB
    unsigned short* zb = (unsigned short*)(ws + 22118656); // 8192*64 bf16 -> 1 MiB
    // total ws usage: ~23.2 MB

    k_zero_counts<<<32, 256, 0, stream>>>(counts);
    k_hist<<<EE / 256, 256, 0, stream>>>(erow, counts);
    k_scan<<<1, 1024, 0, stream>>>(counts, row_start, cursor);
    k_scatter<<<EE / 256, 256, 0, stream>>>(erow, cursor, perm);

    k_gemm1<<<NN / 16, 256, 0, stream>>>(X, W1, sup1);
    k_spmm1v<<<NN / 4, 256, 0, stream>>>(row_start, perm, ecol, eval, sup1, b1, h);
    k_gemm23<<<NN / 16, 128, 0, stream>>>(h, W2, W3, s23);
    k_spmm23v<<<NN / 4, 256, 0, stream>>>(row_start, perm, ecol, eval, s23, b2, b3, noise, zout, zb);
    k_zzt_mfma<<<dim3(64, 64), 256, 0, stream>>>(zb, adj);
}

// Round 3
// 205.940 us; speedup vs baseline: 2.3238x; 1.4055x over previous
//
#include <hip/hip_runtime.h>
#include <math.h>

static constexpr int NN  = 8192;     // nodes
static constexpr int EE  = 262144;   // edges
static constexpr int IND = 512;      // input feature dim
static constexpr int HH1 = 256;

typedef short bf16x8 __attribute__((ext_vector_type(8)));
typedef float f32x4  __attribute__((ext_vector_type(4)));

static __device__ __forceinline__ unsigned short f2bf(float f) {
    unsigned int u = __float_as_uint(f);
    u += 0x7fffu + ((u >> 16) & 1u);   // round-to-nearest-even
    return (unsigned short)(u >> 16);
}
static __device__ __forceinline__ float bf2f(unsigned short h) {
    return __uint_as_float(((unsigned int)h) << 16);
}
static __device__ __forceinline__ float fast_sigmoid(float x) {
    float e = __expf(-x);                      // v_exp path
    return __builtin_amdgcn_rcpf(1.f + e);     // v_rcp, ~1ulp
}

// ---------------- CSR build ----------------

__global__ void k_zero_counts(int* counts) {
    int i = blockIdx.x * 256 + threadIdx.x;
    if (i < NN) counts[i] = 0;
}

__global__ void k_hist(const int* __restrict__ erow, int* counts) {
    int e = blockIdx.x * 256 + threadIdx.x;
    if (e < EE) atomicAdd(&counts[erow[e]], 1);
}

__global__ __launch_bounds__(1024) void k_scan(const int* __restrict__ counts,
                                               int* row_start, int* cursor) {
    __shared__ int part[1024];
    int t = threadIdx.x;
    int base = t * 8;
    int loc[8];
    int s = 0;
#pragma unroll
    for (int i = 0; i < 8; i++) { loc[i] = s; s += counts[base + i]; }
    part[t] = s;
    __syncthreads();
    for (int off = 1; off < 1024; off <<= 1) {
        int v = (t >= off) ? part[t - off] : 0;
        __syncthreads();
        part[t] += v;
        __syncthreads();
    }
    int pre = (t > 0) ? part[t - 1] : 0;
#pragma unroll
    for (int i = 0; i < 8; i++) {
        int v = pre + loc[i];
        row_start[base + i] = v;
        cursor[base + i] = v;
    }
    if (t == 1023) row_start[NN] = part[1023];
}

// scatter edges into row-sorted order, packing (col, val) into one int2
__global__ void k_scatter_pack(const int* __restrict__ erow,
                               const int* __restrict__ ecol,
                               const float* __restrict__ eval,
                               int* cursor, int2* __restrict__ epack) {
    int e = blockIdx.x * 256 + threadIdx.x;
    int r = erow[e];
    int pos = atomicAdd(&cursor[r], 1);
    epack[pos] = make_int2(ecol[e], __float_as_int(eval[e]));
}

// ---------------- prep: split X to bf16 hi/lo; transpose+split W1, [W2|W3] ----------------
__global__ __launch_bounds__(256) void k_prep(const float* __restrict__ X,
                                              const float* __restrict__ W1,
                                              const float* __restrict__ W2,
                                              const float* __restrict__ W3,
                                              unsigned short* __restrict__ Xhi,
                                              unsigned short* __restrict__ Xlo,
                                              unsigned short* __restrict__ W1Thi,
                                              unsigned short* __restrict__ W1Tlo,
                                              unsigned short* __restrict__ W23Thi,
                                              unsigned short* __restrict__ W23Tlo) {
    int b = blockIdx.x;
    if (b < 4096) {
        // X split: 4096 blocks x 256 thr x 4 floats = 8192*512
        int idx = b * 1024 + threadIdx.x * 4;
        float4 x = *(const float4*)&X[idx];
        ushort4 hi, lo;
        hi.x = f2bf(x.x); lo.x = f2bf(x.x - bf2f(hi.x));
        hi.y = f2bf(x.y); lo.y = f2bf(x.y - bf2f(hi.y));
        hi.z = f2bf(x.z); lo.z = f2bf(x.z - bf2f(hi.z));
        hi.w = f2bf(x.w); lo.w = f2bf(x.w - bf2f(hi.w));
        *(ushort4*)&Xhi[idx] = hi;
        *(ushort4*)&Xlo[idx] = lo;
        return;
    }
    __shared__ float tile[32][33];
    int c = threadIdx.x & 31;
    int r0 = threadIdx.x >> 5;   // 0..7
    if (b < 4096 + 128) {
        // W1 [512][256] -> W1T [256][512] hi/lo
        int t = b - 4096;
        int tk = t >> 3;   // 0..15
        int tn = t & 7;    // 0..7
#pragma unroll
        for (int i = 0; i < 4; i++) {
            int r = r0 * 4 + i;
            tile[r][c] = W1[(tk * 32 + r) * HH1 + tn * 32 + c];
        }
        __syncthreads();
#pragma unroll
        for (int i = 0; i < 4; i++) {
            int rr = r0 * 4 + i;
            float v = tile[c][rr];
            unsigned short hi = f2bf(v);
            unsigned short lo = f2bf(v - bf2f(hi));
            int o = (tn * 32 + rr) * IND + tk * 32 + c;
            W1Thi[o] = hi;
            W1Tlo[o] = lo;
        }
    } else {
        // [W2|W3] [256][64]x2 -> W23T [128][256] hi/lo
        int t = b - 4224;  // 0..31
        int tk = t >> 2;   // 0..7
        int tn = t & 3;    // 0..3 ; tn<2 -> W2, else W3
        const float* Wsrc = (tn < 2) ? W2 : W3;
        int nc0 = (tn & 1) * 32;
#pragma unroll
        for (int i = 0; i < 4; i++) {
            int r = r0 * 4 + i;
            tile[r][c] = Wsrc[(tk * 32 + r) * 64 + nc0 + c];
        }
        __syncthreads();
#pragma unroll
        for (int i = 0; i < 4; i++) {
            int rr = r0 * 4 + i;
            float v = tile[c][rr];
            unsigned short hi = f2bf(v);
            unsigned short lo = f2bf(v - bf2f(hi));
            int o = (tn * 32 + rr) * HH1 + tk * 32 + c;
            W23Thi[o] = hi;
            W23Tlo[o] = lo;
        }
    }
}

// ---------------- GEMM1 (bf16x3 MFMA): sup1 = X @ W1, fp32-accurate ----------------
// BM=64, BN=128, 4 waves (2x2), per-wave 32x64, grid 256
__global__ __launch_bounds__(256) void k_gemm1_mfma(const unsigned short* __restrict__ Ahi,
                                                    const unsigned short* __restrict__ Alo,
                                                    const unsigned short* __restrict__ Bhi,
                                                    const unsigned short* __restrict__ Blo,
                                                    float* __restrict__ out) {
    int b = blockIdx.x;
    int bm = b >> 1, bn = b & 1;
    int w = threadIdx.x >> 6, l = threadIdx.x & 63;
    int wm = w >> 1, wn = w & 1;
    int lr = l & 15, kg = l >> 4;
    int row0 = bm * 64 + wm * 32;
    int col0 = bn * 128 + wn * 64;

    f32x4 acc[2][4];
#pragma unroll
    for (int mt = 0; mt < 2; mt++)
#pragma unroll
        for (int nt = 0; nt < 4; nt++) acc[mt][nt] = (f32x4){0.f, 0.f, 0.f, 0.f};

    for (int ks = 0; ks < IND; ks += 32) {
        int ko = ks + kg * 8;
        bf16x8 ah[2], al[2], bh[4], bl[4];
#pragma unroll
        for (int mt = 0; mt < 2; mt++) {
            size_t off = (size_t)(row0 + mt * 16 + lr) * IND + ko;
            ah[mt] = *(const bf16x8*)&Ahi[off];
            al[mt] = *(const bf16x8*)&Alo[off];
        }
#pragma unroll
        for (int nt = 0; nt < 4; nt++) {
            size_t off = (size_t)(col0 + nt * 16 + lr) * IND + ko;
            bh[nt] = *(const bf16x8*)&Bhi[off];
            bl[nt] = *(const bf16x8*)&Blo[off];
        }
#pragma unroll
        for (int mt = 0; mt < 2; mt++)
#pragma unroll
            for (int nt = 0; nt < 4; nt++) {
                acc[mt][nt] = __builtin_amdgcn_mfma_f32_16x16x32_bf16(ah[mt], bh[nt], acc[mt][nt], 0, 0, 0);
                acc[mt][nt] = __builtin_amdgcn_mfma_f32_16x16x32_bf16(ah[mt], bl[nt], acc[mt][nt], 0, 0, 0);
                acc[mt][nt] = __builtin_amdgcn_mfma_f32_16x16x32_bf16(al[mt], bh[nt], acc[mt][nt], 0, 0, 0);
            }
    }
#pragma unroll
    for (int mt = 0; mt < 2; mt++)
#pragma unroll
        for (int nt = 0; nt < 4; nt++)
#pragma unroll
            for (int r = 0; r < 4; r++)
                out[(size_t)(row0 + mt * 16 + kg * 4 + r) * HH1 + col0 + nt * 16 + lr] = acc[mt][nt][r];
}

// ---------------- SpMM1: h = tanh(A @ sup1 + b1), write h as bf16 hi/lo ----------------
__global__ __launch_bounds__(256) void k_spmm1v(const int* __restrict__ row_start,
                                                const int2* __restrict__ epack,
                                                const float* __restrict__ sup,
                                                const float* __restrict__ b1,
                                                unsigned short* __restrict__ hhi,
                                                unsigned short* __restrict__ hlo) {
    int w = threadIdx.x >> 6, l = threadIdx.x & 63;
    int row = blockIdx.x * 4 + w;
    int s = row_start[row], eend = row_start[row + 1];
    const float4* supv = (const float4*)sup;   // sup row = 64 float4
    float4 acc = make_float4(0.f, 0.f, 0.f, 0.f);
    for (int i = s; i < eend; i++) {
        int2 p = epack[i];
        float v = __int_as_float(p.y);
        float4 t = supv[(size_t)p.x * 64 + l];
        acc.x += v * t.x; acc.y += v * t.y; acc.z += v * t.z; acc.w += v * t.w;
    }
    float4 bb = ((const float4*)b1)[l];
    float o0 = tanhf(acc.x + bb.x);
    float o1 = tanhf(acc.y + bb.y);
    float o2 = tanhf(acc.z + bb.z);
    float o3 = tanhf(acc.w + bb.w);
    ushort4 hi, lo;
    hi.x = f2bf(o0); lo.x = f2bf(o0 - bf2f(hi.x));
    hi.y = f2bf(o1); lo.y = f2bf(o1 - bf2f(hi.y));
    hi.z = f2bf(o2); lo.z = f2bf(o2 - bf2f(hi.z));
    hi.w = f2bf(o3); lo.w = f2bf(o3 - bf2f(hi.w));
    size_t o = (size_t)row * HH1 + l * 4;
    *(ushort4*)&hhi[o] = hi;
    *(ushort4*)&hlo[o] = lo;
}

// ---------------- GEMM23 (bf16x3 MFMA): s23 = h @ [W2|W3] ----------------
// BM=32, BN=128, 4 waves (1x4), per-wave 32x32, grid 256
__global__ __launch_bounds__(256) void k_gemm23_mfma(const unsigned short* __restrict__ Ahi,
                                                     const unsigned short* __restrict__ Alo,
                                                     const unsigned short* __restrict__ Bhi,
                                                     const unsigned short* __restrict__ Blo,
                                                     float* __restrict__ out) {
    int bm = blockIdx.x;
    int w = threadIdx.x >> 6, l = threadIdx.x & 63;
    int lr = l & 15, kg = l >> 4;
    int row0 = bm * 32;
    int col0 = w * 32;

    f32x4 acc[2][2];
#pragma unroll
    for (int mt = 0; mt < 2; mt++)
#pragma unroll
        for (int nt = 0; nt < 2; nt++) acc[mt][nt] = (f32x4){0.f, 0.f, 0.f, 0.f};

    for (int ks = 0; ks < HH1; ks += 32) {
        int ko = ks + kg * 8;
        bf16x8 ah[2], al[2], bh[2], bl[2];
#pragma unroll
        for (int mt = 0; mt < 2; mt++) {
            size_t off = (size_t)(row0 + mt * 16 + lr) * HH1 + ko;
            ah[mt] = *(const bf16x8*)&Ahi[off];
            al[mt] = *(const bf16x8*)&Alo[off];
        }
#pragma unroll
        for (int nt = 0; nt < 2; nt++) {
            size_t off = (size_t)(col0 + nt * 16 + lr) * HH1 + ko;
            bh[nt] = *(const bf16x8*)&Bhi[off];
            bl[nt] = *(const bf16x8*)&Blo[off];
        }
#pragma unroll
        for (int mt = 0; mt < 2; mt++)
#pragma unroll
            for (int nt = 0; nt < 2; nt++) {
                acc[mt][nt] = __builtin_amdgcn_mfma_f32_16x16x32_bf16(ah[mt], bh[nt], acc[mt][nt], 0, 0, 0);
                acc[mt][nt] = __builtin_amdgcn_mfma_f32_16x16x32_bf16(ah[mt], bl[nt], acc[mt][nt], 0, 0, 0);
                acc[mt][nt] = __builtin_amdgcn_mfma_f32_16x16x32_bf16(al[mt], bh[nt], acc[mt][nt], 0, 0, 0);
            }
    }
#pragma unroll
    for (int mt = 0; mt < 2; mt++)
#pragma unroll
        for (int nt = 0; nt < 2; nt++)
#pragma unroll
            for (int r = 0; r < 4; r++)
                out[(size_t)(row0 + mt * 16 + kg * 4 + r) * 128 + col0 + nt * 16 + lr] = acc[mt][nt][r];
}

// ---------------- SpMM2+3 + reparameterization ----------------
__global__ __launch_bounds__(256) void k_spmm23v(const int* __restrict__ row_start,
                                                 const int2* __restrict__ epack,
                                                 const float* __restrict__ s23,
                                                 const float* __restrict__ b2,
                                                 const float* __restrict__ b3,
                                                 const float* __restrict__ noise,
                                                 float* __restrict__ zout,
                                                 unsigned short* __restrict__ zb) {
    int w = threadIdx.x >> 6, l = threadIdx.x & 63;
    int row = blockIdx.x * 4 + w;
    int s = row_start[row], eend = row_start[row + 1];
    const float2* sv = (const float2*)s23;   // s23 row = 64 float2
    float2 acc = make_float2(0.f, 0.f);
    for (int i = s; i < eend; i++) {
        int2 p = epack[i];
        float v = __int_as_float(p.y);
        float2 t = sv[(size_t)p.x * 64 + l];
        acc.x += v * t.x; acc.y += v * t.y;
    }
    float bx, by;
    if (l < 32) { bx = b2[2 * l]; by = b2[2 * l + 1]; }
    else        { bx = b3[2 * (l - 32)]; by = b3[2 * (l - 32) + 1]; }
    float t0 = tanhf(acc.x + bx);
    float t1 = tanhf(acc.y + by);
    float u0 = __shfl_xor(t0, 32, 64);
    float u1 = __shfl_xor(t1, 32, 64);
    if (l < 32) {
        float2 nz = ((const float2*)noise)[(size_t)row * 32 + l];
        float z0 = t0 + nz.x * __expf(u0);
        float z1 = t1 + nz.y * __expf(u1);
        ((float2*)zout)[(size_t)row * 32 + l] = make_float2(z0, z1);
        unsigned int p = (unsigned int)f2bf(z0) | ((unsigned int)f2bf(z1) << 16);
        ((unsigned int*)zb)[(size_t)row * 32 + l] = p;
    }
}

// ---------------- adj = sigmoid(z @ z^T) via MFMA bf16, no LDS ----------------
__global__ __launch_bounds__(256) void k_zzt_mfma(const unsigned short* __restrict__ zb,
                                                  float* __restrict__ adj) {
    int bi = blockIdx.y, bj = blockIdx.x;
    int tid = threadIdx.x;
    int w = tid >> 6, l = tid & 63;
    int lr = l & 15, kg = l >> 4;
    const int i0 = bi * 128 + w * 32;
    const int j0 = bj * 128;

    bf16x8 a[2][2];
#pragma unroll
    for (int mt = 0; mt < 2; mt++)
#pragma unroll
        for (int kk = 0; kk < 2; kk++)
            a[mt][kk] = *(const bf16x8*)&zb[(size_t)(i0 + mt * 16 + lr) * 64 + kk * 32 + kg * 8];

    f32x4 acc[2][8];
#pragma unroll
    for (int mt = 0; mt < 2; mt++)
#pragma unroll
        for (int nt = 0; nt < 8; nt++)
            acc[mt][nt] = (f32x4){0.f, 0.f, 0.f, 0.f};

#pragma unroll
    for (int nt = 0; nt < 8; nt++) {
        bf16x8 b0 = *(const bf16x8*)&zb[(size_t)(j0 + nt * 16 + lr) * 64 + 0  + kg * 8];
        bf16x8 b1 = *(const bf16x8*)&zb[(size_t)(j0 + nt * 16 + lr) * 64 + 32 + kg * 8];
        acc[0][nt] = __builtin_amdgcn_mfma_f32_16x16x32_bf16(a[0][0], b0, acc[0][nt], 0, 0, 0);
        acc[0][nt] = __builtin_amdgcn_mfma_f32_16x16x32_bf16(a[0][1], b1, acc[0][nt], 0, 0, 0);
        acc[1][nt] = __builtin_amdgcn_mfma_f32_16x16x32_bf16(a[1][0], b0, acc[1][nt], 0, 0, 0);
        acc[1][nt] = __builtin_amdgcn_mfma_f32_16x16x32_bf16(a[1][1], b1, acc[1][nt], 0, 0, 0);
    }

#pragma unroll
    for (int mt = 0; mt < 2; mt++) {
#pragma unroll
        for (int nt = 0; nt < 8; nt++) {
            size_t rbase = (size_t)(i0 + mt * 16 + kg * 4);
            size_t col = (size_t)(j0 + nt * 16 + lr);
#pragma unroll
            for (int r = 0; r < 4; r++) {
                adj[(rbase + r) * NN + col] = fast_sigmoid(acc[mt][nt][r]);
            }
        }
    }
}

extern "C" void kernel_launch(void* const* d_in, const int* in_sizes, int n_in,
                              void* d_out, int out_size, void* d_ws, size_t ws_size,
                              hipStream_t stream) {
    const int*   erow  = (const int*)d_in[0];
    const int*   ecol  = (const int*)d_in[1];
    const float* eval  = (const float*)d_in[2];
    const float* X     = (const float*)d_in[3];
    const float* W1    = (const float*)d_in[4];
    const float* b1    = (const float*)d_in[5];
    const float* W2    = (const float*)d_in[6];
    const float* b2    = (const float*)d_in[7];
    const float* W3    = (const float*)d_in[8];
    const float* b3    = (const float*)d_in[9];
    const float* noise = (const float*)d_in[10];

    float* adj  = (float*)d_out;
    float* zout = (float*)d_out + (size_t)NN * NN;

    // small scratch in d_ws (<4 MB, well under proven capacity)
    char* ws = (char*)d_ws;
    int*  counts    = (int*)(ws + 0);
    int*  row_start = (int*)(ws + 32768);
    int*  cursor    = (int*)(ws + 69632);
    int2* epack     = (int2*)(ws + 102400);                    // 2 MiB
    unsigned short* W1Thi  = (unsigned short*)(ws + 2199552);  // 256 KiB
    unsigned short* W1Tlo  = (unsigned short*)(ws + 2461696);  // 256 KiB
    unsigned short* W23Thi = (unsigned short*)(ws + 2723840);  // 64 KiB
    unsigned short* W23Tlo = (unsigned short*)(ws + 2789376);  // 64 KiB
    unsigned short* zb     = (unsigned short*)(ws + 2854912);  // 1 MiB

    // large temporaries live in the adj region of d_out (fully overwritten by k_zzt last)
    char* ob = (char*)d_out;
    unsigned short* Xhi = (unsigned short*)(ob + 0);          // 8 MiB
    unsigned short* Xlo = (unsigned short*)(ob + 8388608);    // 8 MiB
    float*          sup1 = (float*)(ob + 16777216);           // 8 MiB
    unsigned short* hhi = (unsigned short*)(ob + 25165824);   // 4 MiB
    unsigned short* hlo = (unsigned short*)(ob + 29360128);   // 4 MiB
    float*          s23 = (float*)(ob + 33554432);            // 4 MiB

    k_zero_counts<<<32, 256, 0, stream>>>(counts);
    k_hist<<<EE / 256, 256, 0, stream>>>(erow, counts);
    k_scan<<<1, 1024, 0, stream>>>(counts, row_start, cursor);
    k_scatter_pack<<<EE / 256, 256, 0, stream>>>(erow, ecol, eval, cursor, epack);

    k_prep<<<4256, 256, 0, stream>>>(X, W1, W2, W3, Xhi, Xlo, W1Thi, W1Tlo, W23Thi, W23Tlo);
    k_gemm1_mfma<<<256, 256, 0, stream>>>(Xhi, Xlo, W1Thi, W1Tlo, sup1);
    k_spmm1v<<<NN / 4, 256, 0, stream>>>(row_start, epack, sup1, b1, hhi, hlo);
    k_gemm23_mfma<<<256, 256, 0, stream>>>(hhi, hlo, W23Thi, W23Tlo, s23);
    k_spmm23v<<<NN / 4, 256, 0, stream>>>(row_start, epack, s23, b2, b3, noise, zout, zb);
    k_zzt_mfma<<<dim3(64, 64), 256, 0, stream>>>(zb, adj);
}

// Round 5
// 196.105 us; speedup vs baseline: 2.4404x; 1.0502x over previous
//
#include <hip/hip_runtime.h>
#include <math.h>

static constexpr int NN  = 8192;     // nodes
static constexpr int EE  = 262144;   // edges
static constexpr int IND = 512;      // input feature dim
static constexpr int HH1 = 256;

typedef short    bf16x8 __attribute__((ext_vector_type(8)));
typedef _Float16 f16x8  __attribute__((ext_vector_type(8)));
typedef _Float16 f16x4  __attribute__((ext_vector_type(4)));
typedef _Float16 f16x2  __attribute__((ext_vector_type(2)));
typedef float    f32x4  __attribute__((ext_vector_type(4)));

static __device__ __forceinline__ unsigned short f2bf(float f) {
    unsigned int u = __float_as_uint(f);
    u += 0x7fffu + ((u >> 16) & 1u);   // round-to-nearest-even
    return (unsigned short)(u >> 16);
}
static __device__ __forceinline__ float bf2f(unsigned short h) {
    return __uint_as_float(((unsigned int)h) << 16);
}
static __device__ __forceinline__ float fast_sigmoid(float x) {
    float e = __expf(-x);
    return __builtin_amdgcn_rcpf(1.f + e);
}

// ---------------- CSR build ----------------

__global__ void k_zero_counts(int* counts) {
    int i = blockIdx.x * 256 + threadIdx.x;
    if (i < NN) counts[i] = 0;
}

__global__ void k_hist(const int* __restrict__ erow, int* counts) {
    int e = blockIdx.x * 256 + threadIdx.x;
    if (e < EE) atomicAdd(&counts[erow[e]], 1);
}

__global__ __launch_bounds__(1024) void k_scan(const int* __restrict__ counts,
                                               int* row_start, int* cursor) {
    __shared__ int part[1024];
    int t = threadIdx.x;
    int base = t * 8;
    int loc[8];
    int s = 0;
#pragma unroll
    for (int i = 0; i < 8; i++) { loc[i] = s; s += counts[base + i]; }
    part[t] = s;
    __syncthreads();
    for (int off = 1; off < 1024; off <<= 1) {
        int v = (t >= off) ? part[t - off] : 0;
        __syncthreads();
        part[t] += v;
        __syncthreads();
    }
    int pre = (t > 0) ? part[t - 1] : 0;
#pragma unroll
    for (int i = 0; i < 8; i++) {
        int v = pre + loc[i];
        row_start[base + i] = v;
        cursor[base + i] = v;
    }
    if (t == 1023) row_start[NN] = part[1023];
}

__global__ void k_scatter_pack(const int* __restrict__ erow,
                               const int* __restrict__ ecol,
                               const float* __restrict__ eval,
                               int* cursor, int2* __restrict__ epack) {
    int e = blockIdx.x * 256 + threadIdx.x;
    int r = erow[e];
    int pos = atomicAdd(&cursor[r], 1);
    epack[pos] = make_int2(ecol[e], __float_as_int(eval[e]));
}

// ---------------- prep: split X to bf16 hi/lo; transpose+split W1, [W2|W3] ----------------
__global__ __launch_bounds__(256) void k_prep(const float* __restrict__ X,
                                              const float* __restrict__ W1,
                                              const float* __restrict__ W2,
                                              const float* __restrict__ W3,
                                              unsigned short* __restrict__ Xhi,
                                              unsigned short* __restrict__ Xlo,
                                              unsigned short* __restrict__ W1Thi,
                                              unsigned short* __restrict__ W1Tlo,
                                              unsigned short* __restrict__ W23Thi,
                                              unsigned short* __restrict__ W23Tlo) {
    int b = blockIdx.x;
    if (b < 4096) {
        // X split: 4096 blocks x 256 thr x 4 floats = 8192*512
        int idx = b * 1024 + threadIdx.x * 4;
        float4 x = *(const float4*)&X[idx];
        ushort4 hi, lo;
        hi.x = f2bf(x.x); lo.x = f2bf(x.x - bf2f(hi.x));
        hi.y = f2bf(x.y); lo.y = f2bf(x.y - bf2f(hi.y));
        hi.z = f2bf(x.z); lo.z = f2bf(x.z - bf2f(hi.z));
        hi.w = f2bf(x.w); lo.w = f2bf(x.w - bf2f(hi.w));
        *(ushort4*)&Xhi[idx] = hi;
        *(ushort4*)&Xlo[idx] = lo;
        return;
    }
    __shared__ float tile[32][33];
    int c = threadIdx.x & 31;
    int r0 = threadIdx.x >> 5;   // 0..7
    if (b < 4096 + 128) {
        // W1 [512][256] -> W1T [256][512] hi/lo
        int t = b - 4096;
        int tk = t >> 3;   // 0..15
        int tn = t & 7;    // 0..7
#pragma unroll
        for (int i = 0; i < 4; i++) {
            int r = r0 * 4 + i;
            tile[r][c] = W1[(tk * 32 + r) * HH1 + tn * 32 + c];
        }
        __syncthreads();
#pragma unroll
        for (int i = 0; i < 4; i++) {
            int rr = r0 * 4 + i;
            float v = tile[c][rr];
            unsigned short hi = f2bf(v);
            unsigned short lo = f2bf(v - bf2f(hi));
            int o = (tn * 32 + rr) * IND + tk * 32 + c;
            W1Thi[o] = hi;
            W1Tlo[o] = lo;
        }
    } else {
        // [W2|W3] [256][64]x2 -> W23T [128][256] hi/lo
        int t = b - 4224;  // 0..31
        int tk = t >> 2;   // 0..7
        int tn = t & 3;    // tn<2 -> W2, else W3
        const float* Wsrc = (tn < 2) ? W2 : W3;
        int nc0 = (tn & 1) * 32;
#pragma unroll
        for (int i = 0; i < 4; i++) {
            int r = r0 * 4 + i;
            tile[r][c] = Wsrc[(tk * 32 + r) * 64 + nc0 + c];
        }
        __syncthreads();
#pragma unroll
        for (int i = 0; i < 4; i++) {
            int rr = r0 * 4 + i;
            float v = tile[c][rr];
            unsigned short hi = f2bf(v);
            unsigned short lo = f2bf(v - bf2f(hi));
            int o = (tn * 32 + rr) * HH1 + tk * 32 + c;
            W23Thi[o] = hi;
            W23Tlo[o] = lo;
        }
    }
}

// ---------------- GEMM1 (bf16x3 MFMA, fp32-accurate): sup1h = fp16(X @ W1) ----------------
// BM=64, BN=128, 4 waves (2x2), per-wave 32x64, grid 256
__global__ __launch_bounds__(256) void k_gemm1_mfma(const unsigned short* __restrict__ Ahi,
                                                    const unsigned short* __restrict__ Alo,
                                                    const unsigned short* __restrict__ Bhi,
                                                    const unsigned short* __restrict__ Blo,
                                                    _Float16* __restrict__ out) {
    int b = blockIdx.x;
    int bm = b >> 1, bn = b & 1;
    int w = threadIdx.x >> 6, l = threadIdx.x & 63;
    int wm = w >> 1, wn = w & 1;
    int lr = l & 15, kg = l >> 4;
    int row0 = bm * 64 + wm * 32;
    int col0 = bn * 128 + wn * 64;

    f32x4 acc[2][4];
#pragma unroll
    for (int mt = 0; mt < 2; mt++)
#pragma unroll
        for (int nt = 0; nt < 4; nt++) acc[mt][nt] = (f32x4){0.f, 0.f, 0.f, 0.f};

    for (int ks = 0; ks < IND; ks += 32) {
        int ko = ks + kg * 8;
        bf16x8 ah[2], al[2], bh[4], bl[4];
#pragma unroll
        for (int mt = 0; mt < 2; mt++) {
            size_t off = (size_t)(row0 + mt * 16 + lr) * IND + ko;
            ah[mt] = *(const bf16x8*)&Ahi[off];
            al[mt] = *(const bf16x8*)&Alo[off];
        }
#pragma unroll
        for (int nt = 0; nt < 4; nt++) {
            size_t off = (size_t)(col0 + nt * 16 + lr) * IND + ko;
            bh[nt] = *(const bf16x8*)&Bhi[off];
            bl[nt] = *(const bf16x8*)&Blo[off];
        }
#pragma unroll
        for (int mt = 0; mt < 2; mt++)
#pragma unroll
            for (int nt = 0; nt < 4; nt++) {
                acc[mt][nt] = __builtin_amdgcn_mfma_f32_16x16x32_bf16(ah[mt], bh[nt], acc[mt][nt], 0, 0, 0);
                acc[mt][nt] = __builtin_amdgcn_mfma_f32_16x16x32_bf16(ah[mt], bl[nt], acc[mt][nt], 0, 0, 0);
                acc[mt][nt] = __builtin_amdgcn_mfma_f32_16x16x32_bf16(al[mt], bh[nt], acc[mt][nt], 0, 0, 0);
            }
    }
#pragma unroll
    for (int mt = 0; mt < 2; mt++)
#pragma unroll
        for (int nt = 0; nt < 4; nt++)
#pragma unroll
            for (int r = 0; r < 4; r++)
                out[(size_t)(row0 + mt * 16 + kg * 4 + r) * HH1 + col0 + nt * 16 + lr] =
                    (_Float16)acc[mt][nt][r];
}

// ---------------- SpMM1: h = tanh(A @ sup1h + b1) -> bf16 hi/lo ----------------
__global__ __launch_bounds__(256) void k_spmm1v(const int* __restrict__ row_start,
                                                const int2* __restrict__ epack,
                                                const _Float16* __restrict__ sup,
                                                const float* __restrict__ b1,
                                                unsigned short* __restrict__ hhi,
                                                unsigned short* __restrict__ hlo) {
    int w = threadIdx.x >> 6, l = threadIdx.x & 63;
    int row = blockIdx.x * 4 + w;
    int s = row_start[row], eend = row_start[row + 1];
    float4 acc = make_float4(0.f, 0.f, 0.f, 0.f);
    int i = s;
    for (; i + 2 <= eend; i += 2) {
        int2 p0 = epack[i];
        int2 p1 = epack[i + 1];
        f16x4 t0 = *(const f16x4*)&sup[(size_t)p0.x * HH1 + l * 4];
        f16x4 t1 = *(const f16x4*)&sup[(size_t)p1.x * HH1 + l * 4];
        float v0 = __int_as_float(p0.y), v1 = __int_as_float(p1.y);
        acc.x += v0 * (float)t0[0] + v1 * (float)t1[0];
        acc.y += v0 * (float)t0[1] + v1 * (float)t1[1];
        acc.z += v0 * (float)t0[2] + v1 * (float)t1[2];
        acc.w += v0 * (float)t0[3] + v1 * (float)t1[3];
    }
    if (i < eend) {
        int2 p0 = epack[i];
        f16x4 t0 = *(const f16x4*)&sup[(size_t)p0.x * HH1 + l * 4];
        float v0 = __int_as_float(p0.y);
        acc.x += v0 * (float)t0[0];
        acc.y += v0 * (float)t0[1];
        acc.z += v0 * (float)t0[2];
        acc.w += v0 * (float)t0[3];
    }
    float4 bb = ((const float4*)b1)[l];
    float o0 = tanhf(acc.x + bb.x);
    float o1 = tanhf(acc.y + bb.y);
    float o2 = tanhf(acc.z + bb.z);
    float o3 = tanhf(acc.w + bb.w);
    ushort4 hi, lo;
    hi.x = f2bf(o0); lo.x = f2bf(o0 - bf2f(hi.x));
    hi.y = f2bf(o1); lo.y = f2bf(o1 - bf2f(hi.y));
    hi.z = f2bf(o2); lo.z = f2bf(o2 - bf2f(hi.z));
    hi.w = f2bf(o3); lo.w = f2bf(o3 - bf2f(hi.w));
    size_t o = (size_t)row * HH1 + l * 4;
    *(ushort4*)&hhi[o] = hi;
    *(ushort4*)&hlo[o] = lo;
}

// ---------------- GEMM23 (bf16x3 MFMA): s23h = fp16(h @ [W2|W3]) ----------------
// BM=32, 4 waves (1x4), per-wave 32x32, grid 256
__global__ __launch_bounds__(256) void k_gemm23_mfma(const unsigned short* __restrict__ Ahi,
                                                     const unsigned short* __restrict__ Alo,
                                                     const unsigned short* __restrict__ Bhi,
                                                     const unsigned short* __restrict__ Blo,
                                                     _Float16* __restrict__ out) {
    int bm = blockIdx.x;
    int w = threadIdx.x >> 6, l = threadIdx.x & 63;
    int lr = l & 15, kg = l >> 4;
    int row0 = bm * 32;
    int col0 = w * 32;

    f32x4 acc[2][2];
#pragma unroll
    for (int mt = 0; mt < 2; mt++)
#pragma unroll
        for (int nt = 0; nt < 2; nt++) acc[mt][nt] = (f32x4){0.f, 0.f, 0.f, 0.f};

    for (int ks = 0; ks < HH1; ks += 32) {
        int ko = ks + kg * 8;
        bf16x8 ah[2], al[2], bh[2], bl[2];
#pragma unroll
        for (int mt = 0; mt < 2; mt++) {
            size_t off = (size_t)(row0 + mt * 16 + lr) * HH1 + ko;
            ah[mt] = *(const bf16x8*)&Ahi[off];
            al[mt] = *(const bf16x8*)&Alo[off];
        }
#pragma unroll
        for (int nt = 0; nt < 2; nt++) {
            size_t off = (size_t)(col0 + nt * 16 + lr) * HH1 + ko;
            bh[nt] = *(const bf16x8*)&Bhi[off];
            bl[nt] = *(const bf16x8*)&Blo[off];
        }
#pragma unroll
        for (int mt = 0; mt < 2; mt++)
#pragma unroll
            for (int nt = 0; nt < 2; nt++) {
                acc[mt][nt] = __builtin_amdgcn_mfma_f32_16x16x32_bf16(ah[mt], bh[nt], acc[mt][nt], 0, 0, 0);
                acc[mt][nt] = __builtin_amdgcn_mfma_f32_16x16x32_bf16(ah[mt], bl[nt], acc[mt][nt], 0, 0, 0);
                acc[mt][nt] = __builtin_amdgcn_mfma_f32_16x16x32_bf16(al[mt], bh[nt], acc[mt][nt], 0, 0, 0);
            }
    }
#pragma unroll
    for (int mt = 0; mt < 2; mt++)
#pragma unroll
        for (int nt = 0; nt < 2; nt++)
#pragma unroll
            for (int r = 0; r < 4; r++)
                out[(size_t)(row0 + mt * 16 + kg * 4 + r) * 128 + col0 + nt * 16 + lr] =
                    (_Float16)acc[mt][nt][r];
}

// ---------------- SpMM2+3 + reparameterization -> zout fp32, zh fp16 ----------------
__global__ __launch_bounds__(256) void k_spmm23v(const int* __restrict__ row_start,
                                                 const int2* __restrict__ epack,
                                                 const _Float16* __restrict__ s23,
                                                 const float* __restrict__ b2,
                                                 const float* __restrict__ b3,
                                                 const float* __restrict__ noise,
                                                 float* __restrict__ zout,
                                                 _Float16* __restrict__ zh) {
    int w = threadIdx.x >> 6, l = threadIdx.x & 63;
    int row = blockIdx.x * 4 + w;
    int s = row_start[row], eend = row_start[row + 1];
    float ax = 0.f, ay = 0.f;
    int i = s;
    for (; i + 2 <= eend; i += 2) {
        int2 p0 = epack[i];
        int2 p1 = epack[i + 1];
        f16x2 t0 = *(const f16x2*)&s23[(size_t)p0.x * 128 + l * 2];
        f16x2 t1 = *(const f16x2*)&s23[(size_t)p1.x * 128 + l * 2];
        float v0 = __int_as_float(p0.y), v1 = __int_as_float(p1.y);
        ax += v0 * (float)t0[0] + v1 * (float)t1[0];
        ay += v0 * (float)t0[1] + v1 * (float)t1[1];
    }
    if (i < eend) {
        int2 p0 = epack[i];
        f16x2 t0 = *(const f16x2*)&s23[(size_t)p0.x * 128 + l * 2];
        float v0 = __int_as_float(p0.y);
        ax += v0 * (float)t0[0];
        ay += v0 * (float)t0[1];
    }
    float bx, by;
    if (l < 32) { bx = b2[2 * l]; by = b2[2 * l + 1]; }
    else        { bx = b3[2 * (l - 32)]; by = b3[2 * (l - 32) + 1]; }
    float t0 = tanhf(ax + bx);
    float t1 = tanhf(ay + by);
    float u0 = __shfl_xor(t0, 32, 64);   // mean lanes receive log_std partner
    float u1 = __shfl_xor(t1, 32, 64);
    if (l < 32) {
        float2 nz = ((const float2*)noise)[(size_t)row * 32 + l];
        float z0 = t0 + nz.x * __expf(u0);
        float z1 = t1 + nz.y * __expf(u1);
        ((float2*)zout)[(size_t)row * 32 + l] = make_float2(z0, z1);
        *(f16x2*)&zh[(size_t)row * 64 + l * 2] = (f16x2){(_Float16)z0, (_Float16)z1};
    }
}

// ---------------- adj = sigmoid(z @ z^T) via MFMA f16, transposed float4 stores ----------------
// adj is symmetric: block (bi,bj) computes rows [bi*128+w*32,+32) x cols [bj*128,+128)
// and writes the TRANSPOSE (entry (p,q) written exactly once, by block bi=q/128, bj=p/128).
__global__ __launch_bounds__(256) void k_zzt_mfma(const _Float16* __restrict__ zh,
                                                  float* __restrict__ adj) {
    int bi = blockIdx.y, bj = blockIdx.x;
    int tid = threadIdx.x;
    int w = tid >> 6, l = tid & 63;
    int lr = l & 15, kg = l >> 4;
    const int i0 = bi * 128 + w * 32;
    const int j0 = bj * 128;

    f16x8 a[2][2];
#pragma unroll
    for (int mt = 0; mt < 2; mt++)
#pragma unroll
        for (int kk = 0; kk < 2; kk++)
            a[mt][kk] = *(const f16x8*)&zh[(size_t)(i0 + mt * 16 + lr) * 64 + kk * 32 + kg * 8];

    f32x4 acc[2][8];
#pragma unroll
    for (int mt = 0; mt < 2; mt++)
#pragma unroll
        for (int nt = 0; nt < 8; nt++)
            acc[mt][nt] = (f32x4){0.f, 0.f, 0.f, 0.f};

#pragma unroll
    for (int nt = 0; nt < 8; nt++) {
        f16x8 b0 = *(const f16x8*)&zh[(size_t)(j0 + nt * 16 + lr) * 64 + 0  + kg * 8];
        f16x8 b1 = *(const f16x8*)&zh[(size_t)(j0 + nt * 16 + lr) * 64 + 32 + kg * 8];
        acc[0][nt] = __builtin_amdgcn_mfma_f32_16x16x32_f16(a[0][0], b0, acc[0][nt], 0, 0, 0);
        acc[0][nt] = __builtin_amdgcn_mfma_f32_16x16x32_f16(a[0][1], b1, acc[0][nt], 0, 0, 0);
        acc[1][nt] = __builtin_amdgcn_mfma_f32_16x16x32_f16(a[1][0], b0, acc[1][nt], 0, 0, 0);
        acc[1][nt] = __builtin_amdgcn_mfma_f32_16x16x32_f16(a[1][1], b1, acc[1][nt], 0, 0, 0);
    }

#pragma unroll
    for (int mt = 0; mt < 2; mt++) {
#pragma unroll
        for (int nt = 0; nt < 8; nt++) {
            size_t orow = (size_t)(j0 + nt * 16 + lr);
            size_t ocol = (size_t)(i0 + mt * 16 + kg * 4);
            float4 o;
            o.x = fast_sigmoid(acc[mt][nt][0]);
            o.y = fast_sigmoid(acc[mt][nt][1]);
            o.z = fast_sigmoid(acc[mt][nt][2]);
            o.w = fast_sigmoid(acc[mt][nt][3]);
            *(float4*)&adj[orow * NN + ocol] = o;
        }
    }
}

extern "C" void kernel_launch(void* const* d_in, const int* in_sizes, int n_in,
                              void* d_out, int out_size, void* d_ws, size_t ws_size,
                              hipStream_t stream) {
    const int*   erow  = (const int*)d_in[0];
    const int*   ecol  = (const int*)d_in[1];
    const float* eval  = (const float*)d_in[2];
    const float* X     = (const float*)d_in[3];
    const float* W1    = (const float*)d_in[4];
    const float* b1    = (const float*)d_in[5];
    const float* W2    = (const float*)d_in[6];
    const float* b2    = (const float*)d_in[7];
    const float* W3    = (const float*)d_in[8];
    const float* b3    = (const float*)d_in[9];
    const float* noise = (const float*)d_in[10];

    float* adj  = (float*)d_out;
    float* zout = (float*)d_out + (size_t)NN * NN;

    // small scratch in d_ws (~3.9 MB, same budget that passed in R2/R3)
    char* ws = (char*)d_ws;
    int*  counts    = (int*)(ws + 0);
    int*  row_start = (int*)(ws + 32768);
    int*  cursor    = (int*)(ws + 69632);
    int2* epack     = (int2*)(ws + 102400);                    // 2 MiB
    unsigned short* W1Thi  = (unsigned short*)(ws + 2199552);  // 256 KiB
    unsigned short* W1Tlo  = (unsigned short*)(ws + 2461696);  // 256 KiB
    unsigned short* W23Thi = (unsigned short*)(ws + 2723840);  // 64 KiB
    unsigned short* W23Tlo = (unsigned short*)(ws + 2789376);  // 64 KiB
    _Float16*       zh     = (_Float16*)(ws + 2854912);        // 1 MiB

    // large temporaries in the adj region of d_out (fully overwritten by k_zzt last)
    char* ob = (char*)d_out;
    unsigned short* Xhi   = (unsigned short*)(ob + 0);         // 8 MiB
    unsigned short* Xlo   = (unsigned short*)(ob + 8388608);   // 8 MiB
    _Float16*       sup1h = (_Float16*)(ob + 16777216);        // 4 MiB
    unsigned short* hhi   = (unsigned short*)(ob + 20971520);  // 4 MiB
    unsigned short* hlo   = (unsigned short*)(ob + 25165824);  // 4 MiB
    _Float16*       s23h  = (_Float16*)(ob + 29360128);        // 2 MiB

    k_zero_counts<<<32, 256, 0, stream>>>(counts);
    k_hist<<<EE / 256, 256, 0, stream>>>(erow, counts);
    k_scan<<<1, 1024, 0, stream>>>(counts, row_start, cursor);
    k_scatter_pack<<<EE / 256, 256, 0, stream>>>(erow, ecol, eval, cursor, epack);

    k_prep<<<4256, 256, 0, stream>>>(X, W1, W2, W3, Xhi, Xlo, W1Thi, W1Tlo, W23Thi, W23Tlo);
    k_gemm1_mfma<<<256, 256, 0, stream>>>(Xhi, Xlo, W1Thi, W1Tlo, sup1h);
    k_spmm1v<<<NN / 4, 256, 0, stream>>>(row_start, epack, sup1h, b1, hhi, hlo);
    k_gemm23_mfma<<<256, 256, 0, stream>>>(hhi, hlo, W23Thi, W23Tlo, s23h);
    k_spmm23v<<<NN / 4, 256, 0, stream>>>(row_start, epack, s23h, b2, b3, noise, zout, zh);
    k_zzt_mfma<<<dim3(64, 64), 256, 0, stream>>>(zh, adj);
}

// Round 6
// 183.315 us; speedup vs baseline: 2.6106x; 1.0698x over previous
//
#include <hip/hip_runtime.h>
#include <math.h>

static constexpr int NN  = 8192;     // nodes
static constexpr int EE  = 262144;   // edges
static constexpr int IND = 512;      // input feature dim
static constexpr int HH1 = 256;

typedef _Float16 f16x8  __attribute__((ext_vector_type(8)));
typedef _Float16 f16x4  __attribute__((ext_vector_type(4)));
typedef _Float16 f16x2  __attribute__((ext_vector_type(2)));
typedef float    f32x4  __attribute__((ext_vector_type(4)));

static __device__ __forceinline__ float fast_sigmoid(float x) {
    float e = __expf(-x);
    return __builtin_amdgcn_rcpf(1.f + e);
}

// ---------------- CSR build ----------------

__global__ void k_hist(const int* __restrict__ erow, int* counts) {
    int e = blockIdx.x * 256 + threadIdx.x;
    if (e < EE) atomicAdd(&counts[erow[e]], 1);
}

__global__ __launch_bounds__(1024) void k_scan(const int* __restrict__ counts,
                                               int* row_start, int* cursor) {
    __shared__ int part[1024];
    int t = threadIdx.x;
    int base = t * 8;
    int loc[8];
    int s = 0;
#pragma unroll
    for (int i = 0; i < 8; i++) { loc[i] = s; s += counts[base + i]; }
    part[t] = s;
    __syncthreads();
    for (int off = 1; off < 1024; off <<= 1) {
        int v = (t >= off) ? part[t - off] : 0;
        __syncthreads();
        part[t] += v;
        __syncthreads();
    }
    int pre = (t > 0) ? part[t - 1] : 0;
#pragma unroll
    for (int i = 0; i < 8; i++) {
        int v = pre + loc[i];
        row_start[base + i] = v;
        cursor[base + i] = v;
    }
    if (t == 1023) row_start[NN] = part[1023];
}

__global__ void k_scatter_pack(const int* __restrict__ erow,
                               const int* __restrict__ ecol,
                               const float* __restrict__ eval,
                               int* cursor, int2* __restrict__ epack) {
    int e = blockIdx.x * 256 + threadIdx.x;
    int r = erow[e];
    int pos = atomicAdd(&cursor[r], 1);
    epack[pos] = make_int2(ecol[e], __float_as_int(eval[e]));
}

// ---------------- prep: X -> fp16; W1^T -> fp16; [W2|W3]^T -> fp16 ----------------
__global__ __launch_bounds__(256) void k_prep(const float* __restrict__ X,
                                              const float* __restrict__ W1,
                                              const float* __restrict__ W2,
                                              const float* __restrict__ W3,
                                              _Float16* __restrict__ Xh,
                                              _Float16* __restrict__ W1T,
                                              _Float16* __restrict__ W23T) {
    int b = blockIdx.x;
    if (b < 4096) {
        // X: 4096 blocks x 256 thr x 4 floats = 8192*512
        int idx = b * 1024 + threadIdx.x * 4;
        float4 x = *(const float4*)&X[idx];
        f16x4 o = {(_Float16)x.x, (_Float16)x.y, (_Float16)x.z, (_Float16)x.w};
        *(f16x4*)&Xh[idx] = o;
        return;
    }
    __shared__ float tile[32][33];
    int c = threadIdx.x & 31;
    int r0 = threadIdx.x >> 5;   // 0..7
    if (b < 4096 + 128) {
        // W1 [512][256] -> W1T [256][512]
        int t = b - 4096;
        int tk = t >> 3;   // 0..15
        int tn = t & 7;    // 0..7
#pragma unroll
        for (int i = 0; i < 4; i++) {
            int r = r0 * 4 + i;
            tile[r][c] = W1[(tk * 32 + r) * HH1 + tn * 32 + c];
        }
        __syncthreads();
#pragma unroll
        for (int i = 0; i < 4; i++) {
            int rr = r0 * 4 + i;
            W1T[(tn * 32 + rr) * IND + tk * 32 + c] = (_Float16)tile[c][rr];
        }
    } else {
        // [W2|W3] [256][64]x2 -> W23T [128][256]
        int t = b - 4224;  // 0..31
        int tk = t >> 2;   // 0..7
        int tn = t & 3;    // tn<2 -> W2, else W3
        const float* Wsrc = (tn < 2) ? W2 : W3;
        int nc0 = (tn & 1) * 32;
#pragma unroll
        for (int i = 0; i < 4; i++) {
            int r = r0 * 4 + i;
            tile[r][c] = Wsrc[(tk * 32 + r) * 64 + nc0 + c];
        }
        __syncthreads();
#pragma unroll
        for (int i = 0; i < 4; i++) {
            int rr = r0 * 4 + i;
            W23T[(tn * 32 + rr) * HH1 + tk * 32 + c] = (_Float16)tile[c][rr];
        }
    }
}

// ---------------- GEMM1 (f16 MFMA): sup1h = fp16(Xh @ W1T^T) ----------------
// BM=32, BN=128, grid 512 (2 blocks/CU), 4 waves 2x2, per-wave 16x64
__global__ __launch_bounds__(256) void k_gemm1_mfma(const _Float16* __restrict__ A,
                                                    const _Float16* __restrict__ B,
                                                    _Float16* __restrict__ out) {
    int b = blockIdx.x;
    int bm = b >> 1, bn = b & 1;
    int w = threadIdx.x >> 6, l = threadIdx.x & 63;
    int wm = w >> 1, wn = w & 1;
    int lr = l & 15, kg = l >> 4;
    int row0 = bm * 32 + wm * 16;
    int col0 = bn * 128 + wn * 64;

    f32x4 acc[4];
#pragma unroll
    for (int nt = 0; nt < 4; nt++) acc[nt] = (f32x4){0.f, 0.f, 0.f, 0.f};

    for (int ks = 0; ks < IND; ks += 32) {
        int ko = ks + kg * 8;
        f16x8 a = *(const f16x8*)&A[(size_t)(row0 + lr) * IND + ko];
        f16x8 bb[4];
#pragma unroll
        for (int nt = 0; nt < 4; nt++)
            bb[nt] = *(const f16x8*)&B[(size_t)(col0 + nt * 16 + lr) * IND + ko];
#pragma unroll
        for (int nt = 0; nt < 4; nt++)
            acc[nt] = __builtin_amdgcn_mfma_f32_16x16x32_f16(a, bb[nt], acc[nt], 0, 0, 0);
    }
#pragma unroll
    for (int nt = 0; nt < 4; nt++)
#pragma unroll
        for (int r = 0; r < 4; r++)
            out[(size_t)(row0 + kg * 4 + r) * HH1 + col0 + nt * 16 + lr] = (_Float16)acc[nt][r];
}

// ---------------- SpMM1: h = fp16(tanh(A @ sup1h + b1)) ----------------
__global__ __launch_bounds__(256) void k_spmm1v(const int* __restrict__ row_start,
                                                const int2* __restrict__ epack,
                                                const _Float16* __restrict__ sup,
                                                const float* __restrict__ b1,
                                                _Float16* __restrict__ hb) {
    int w = threadIdx.x >> 6, l = threadIdx.x & 63;
    int row = blockIdx.x * 4 + w;
    int s = row_start[row], eend = row_start[row + 1];
    float4 acc = make_float4(0.f, 0.f, 0.f, 0.f);
    int i = s;
    for (; i + 4 <= eend; i += 4) {
        int2 p0 = epack[i];
        int2 p1 = epack[i + 1];
        int2 p2 = epack[i + 2];
        int2 p3 = epack[i + 3];
        f16x4 t0 = *(const f16x4*)&sup[(size_t)p0.x * HH1 + l * 4];
        f16x4 t1 = *(const f16x4*)&sup[(size_t)p1.x * HH1 + l * 4];
        f16x4 t2 = *(const f16x4*)&sup[(size_t)p2.x * HH1 + l * 4];
        f16x4 t3 = *(const f16x4*)&sup[(size_t)p3.x * HH1 + l * 4];
        float v0 = __int_as_float(p0.y), v1 = __int_as_float(p1.y);
        float v2 = __int_as_float(p2.y), v3 = __int_as_float(p3.y);
        acc.x += v0 * (float)t0[0] + v1 * (float)t1[0] + v2 * (float)t2[0] + v3 * (float)t3[0];
        acc.y += v0 * (float)t0[1] + v1 * (float)t1[1] + v2 * (float)t2[1] + v3 * (float)t3[1];
        acc.z += v0 * (float)t0[2] + v1 * (float)t1[2] + v2 * (float)t2[2] + v3 * (float)t3[2];
        acc.w += v0 * (float)t0[3] + v1 * (float)t1[3] + v2 * (float)t2[3] + v3 * (float)t3[3];
    }
    for (; i < eend; i++) {
        int2 p0 = epack[i];
        f16x4 t0 = *(const f16x4*)&sup[(size_t)p0.x * HH1 + l * 4];
        float v0 = __int_as_float(p0.y);
        acc.x += v0 * (float)t0[0];
        acc.y += v0 * (float)t0[1];
        acc.z += v0 * (float)t0[2];
        acc.w += v0 * (float)t0[3];
    }
    float4 bb = ((const float4*)b1)[l];
    f16x4 o;
    o[0] = (_Float16)tanhf(acc.x + bb.x);
    o[1] = (_Float16)tanhf(acc.y + bb.y);
    o[2] = (_Float16)tanhf(acc.z + bb.z);
    o[3] = (_Float16)tanhf(acc.w + bb.w);
    *(f16x4*)&hb[(size_t)row * HH1 + l * 4] = o;
}

// ---------------- GEMM23 (f16 MFMA): s23h = fp16(hb @ W23T^T) ----------------
// BM=16, grid 512, 4 waves each 16x32
__global__ __launch_bounds__(256) void k_gemm23_mfma(const _Float16* __restrict__ A,
                                                     const _Float16* __restrict__ B,
                                                     _Float16* __restrict__ out) {
    int bm = blockIdx.x;
    int w = threadIdx.x >> 6, l = threadIdx.x & 63;
    int lr = l & 15, kg = l >> 4;
    int row0 = bm * 16;
    int col0 = w * 32;

    f32x4 acc[2];
#pragma unroll
    for (int nt = 0; nt < 2; nt++) acc[nt] = (f32x4){0.f, 0.f, 0.f, 0.f};

    for (int ks = 0; ks < HH1; ks += 32) {
        int ko = ks + kg * 8;
        f16x8 a = *(const f16x8*)&A[(size_t)(row0 + lr) * HH1 + ko];
        f16x8 bb[2];
#pragma unroll
        for (int nt = 0; nt < 2; nt++)
            bb[nt] = *(const f16x8*)&B[(size_t)(col0 + nt * 16 + lr) * HH1 + ko];
#pragma unroll
        for (int nt = 0; nt < 2; nt++)
            acc[nt] = __builtin_amdgcn_mfma_f32_16x16x32_f16(a, bb[nt], acc[nt], 0, 0, 0);
    }
#pragma unroll
    for (int nt = 0; nt < 2; nt++)
#pragma unroll
        for (int r = 0; r < 4; r++)
            out[(size_t)(row0 + kg * 4 + r) * 128 + col0 + nt * 16 + lr] = (_Float16)acc[nt][r];
}

// ---------------- SpMM2+3 + reparameterization -> zout fp32, zh fp16 ----------------
__global__ __launch_bounds__(256) void k_spmm23v(const int* __restrict__ row_start,
                                                 const int2* __restrict__ epack,
                                                 const _Float16* __restrict__ s23,
                                                 const float* __restrict__ b2,
                                                 const float* __restrict__ b3,
                                                 const float* __restrict__ noise,
                                                 float* __restrict__ zout,
                                                 _Float16* __restrict__ zh) {
    int w = threadIdx.x >> 6, l = threadIdx.x & 63;
    int row = blockIdx.x * 4 + w;
    int s = row_start[row], eend = row_start[row + 1];
    float ax = 0.f, ay = 0.f;
    int i = s;
    for (; i + 4 <= eend; i += 4) {
        int2 p0 = epack[i];
        int2 p1 = epack[i + 1];
        int2 p2 = epack[i + 2];
        int2 p3 = epack[i + 3];
        f16x2 t0 = *(const f16x2*)&s23[(size_t)p0.x * 128 + l * 2];
        f16x2 t1 = *(const f16x2*)&s23[(size_t)p1.x * 128 + l * 2];
        f16x2 t2 = *(const f16x2*)&s23[(size_t)p2.x * 128 + l * 2];
        f16x2 t3 = *(const f16x2*)&s23[(size_t)p3.x * 128 + l * 2];
        float v0 = __int_as_float(p0.y), v1 = __int_as_float(p1.y);
        float v2 = __int_as_float(p2.y), v3 = __int_as_float(p3.y);
        ax += v0 * (float)t0[0] + v1 * (float)t1[0] + v2 * (float)t2[0] + v3 * (float)t3[0];
        ay += v0 * (float)t0[1] + v1 * (float)t1[1] + v2 * (float)t2[1] + v3 * (float)t3[1];
    }
    for (; i < eend; i++) {
        int2 p0 = epack[i];
        f16x2 t0 = *(const f16x2*)&s23[(size_t)p0.x * 128 + l * 2];
        float v0 = __int_as_float(p0.y);
        ax += v0 * (float)t0[0];
        ay += v0 * (float)t0[1];
    }
    float bx, by;
    if (l < 32) { bx = b2[2 * l]; by = b2[2 * l + 1]; }
    else        { bx = b3[2 * (l - 32)]; by = b3[2 * (l - 32) + 1]; }
    float t0 = tanhf(ax + bx);
    float t1 = tanhf(ay + by);
    float u0 = __shfl_xor(t0, 32, 64);   // mean lanes receive log_std partner
    float u1 = __shfl_xor(t1, 32, 64);
    if (l < 32) {
        float2 nz = ((const float2*)noise)[(size_t)row * 32 + l];
        float z0 = t0 + nz.x * __expf(u0);
        float z1 = t1 + nz.y * __expf(u1);
        ((float2*)zout)[(size_t)row * 32 + l] = make_float2(z0, z1);
        *(f16x2*)&zh[(size_t)row * 64 + l * 2] = (f16x2){(_Float16)z0, (_Float16)z1};
    }
}

// ---------------- adj = sigmoid(z @ z^T) via MFMA f16, transposed float4 stores ----------------
// adj symmetric: block (bi,bj) computes rows [bi*128+w*32,+32) x cols [bj*128,+128)
// and writes the TRANSPOSE (entry (p,q) written exactly once, by block bi=q/128, bj=p/128).
__global__ __launch_bounds__(256) void k_zzt_mfma(const _Float16* __restrict__ zh,
                                                  float* __restrict__ adj) {
    int bi = blockIdx.y, bj = blockIdx.x;
    int tid = threadIdx.x;
    int w = tid >> 6, l = tid & 63;
    int lr = l & 15, kg = l >> 4;
    const int i0 = bi * 128 + w * 32;
    const int j0 = bj * 128;

    f16x8 a[2][2];
#pragma unroll
    for (int mt = 0; mt < 2; mt++)
#pragma unroll
        for (int kk = 0; kk < 2; kk++)
            a[mt][kk] = *(const f16x8*)&zh[(size_t)(i0 + mt * 16 + lr) * 64 + kk * 32 + kg * 8];

    f32x4 acc[2][8];
#pragma unroll
    for (int mt = 0; mt < 2; mt++)
#pragma unroll
        for (int nt = 0; nt < 8; nt++)
            acc[mt][nt] = (f32x4){0.f, 0.f, 0.f, 0.f};

#pragma unroll
    for (int nt = 0; nt < 8; nt++) {
        f16x8 b0 = *(const f16x8*)&zh[(size_t)(j0 + nt * 16 + lr) * 64 + 0  + kg * 8];
        f16x8 b1 = *(const f16x8*)&zh[(size_t)(j0 + nt * 16 + lr) * 64 + 32 + kg * 8];
        acc[0][nt] = __builtin_amdgcn_mfma_f32_16x16x32_f16(a[0][0], b0, acc[0][nt], 0, 0, 0);
        acc[0][nt] = __builtin_amdgcn_mfma_f32_16x16x32_f16(a[0][1], b1, acc[0][nt], 0, 0, 0);
        acc[1][nt] = __builtin_amdgcn_mfma_f32_16x16x32_f16(a[1][0], b0, acc[1][nt], 0, 0, 0);
        acc[1][nt] = __builtin_amdgcn_mfma_f32_16x16x32_f16(a[1][1], b1, acc[1][nt], 0, 0, 0);
    }

#pragma unroll
    for (int mt = 0; mt < 2; mt++) {
#pragma unroll
        for (int nt = 0; nt < 8; nt++) {
            size_t orow = (size_t)(j0 + nt * 16 + lr);
            size_t ocol = (size_t)(i0 + mt * 16 + kg * 4);
            float4 o;
            o.x = fast_sigmoid(acc[mt][nt][0]);
            o.y = fast_sigmoid(acc[mt][nt][1]);
            o.z = fast_sigmoid(acc[mt][nt][2]);
            o.w = fast_sigmoid(acc[mt][nt][3]);
            *(float4*)&adj[orow * NN + ocol] = o;
        }
    }
}

extern "C" void kernel_launch(void* const* d_in, const int* in_sizes, int n_in,
                              void* d_out, int out_size, void* d_ws, size_t ws_size,
                              hipStream_t stream) {
    const int*   erow  = (const int*)d_in[0];
    const int*   ecol  = (const int*)d_in[1];
    const float* eval  = (const float*)d_in[2];
    const float* X     = (const float*)d_in[3];
    const float* W1    = (const float*)d_in[4];
    const float* b1    = (const float*)d_in[5];
    const float* W2    = (const float*)d_in[6];
    const float* b2    = (const float*)d_in[7];
    const float* W3    = (const float*)d_in[8];
    const float* b3    = (const float*)d_in[9];
    const float* noise = (const float*)d_in[10];

    float* adj  = (float*)d_out;
    float* zout = (float*)d_out + (size_t)NN * NN;

    // small scratch in d_ws (~3.5 MB)
    char* ws = (char*)d_ws;
    int*  counts    = (int*)(ws + 0);
    int*  row_start = (int*)(ws + 32768);
    int*  cursor    = (int*)(ws + 69632);
    int2* epack     = (int2*)(ws + 102400);              // 2 MiB
    _Float16* W1T   = (_Float16*)(ws + 2199552);         // 256 KiB
    _Float16* W23T  = (_Float16*)(ws + 2461696);         // 64 KiB
    _Float16* zh    = (_Float16*)(ws + 2527232);         // 1 MiB

    // large temporaries in the adj region of d_out (fully overwritten by k_zzt last)
    char* ob = (char*)d_out;
    _Float16* Xh    = (_Float16*)(ob + 0);               // 8 MiB
    _Float16* sup1h = (_Float16*)(ob + 8388608);         // 4 MiB
    _Float16* hb    = (_Float16*)(ob + 12582912);        // 4 MiB
    _Float16* s23h  = (_Float16*)(ob + 16777216);        // 2 MiB

    hipMemsetAsync(counts, 0, NN * sizeof(int), stream);
    k_hist<<<EE / 256, 256, 0, stream>>>(erow, counts);
    k_scan<<<1, 1024, 0, stream>>>(counts, row_start, cursor);
    k_scatter_pack<<<EE / 256, 256, 0, stream>>>(erow, ecol, eval, cursor, epack);

    k_prep<<<4256, 256, 0, stream>>>(X, W1, W2, W3, Xh, W1T, W23T);
    k_gemm1_mfma<<<512, 256, 0, stream>>>(Xh, W1T, sup1h);
    k_spmm1v<<<NN / 4, 256, 0, stream>>>(row_start, epack, sup1h, b1, hb);
    k_gemm23_mfma<<<512, 256, 0, stream>>>(hb, W23T, s23h);
    k_spmm23v<<<NN / 4, 256, 0, stream>>>(row_start, epack, s23h, b2, b3, noise, zout, zh);
    k_zzt_mfma<<<dim3(64, 64), 256, 0, stream>>>(zh, adj);
}

// Round 7
// 168.176 us; speedup vs baseline: 2.8456x; 1.0900x over previous
//
#include <hip/hip_runtime.h>
#include <math.h>

static constexpr int NN  = 8192;     // nodes
static constexpr int EE  = 262144;   // edges
static constexpr int IND = 512;      // input feature dim
static constexpr int HH1 = 256;

typedef _Float16 f16x8  __attribute__((ext_vector_type(8)));
typedef _Float16 f16x4  __attribute__((ext_vector_type(4)));
typedef _Float16 f16x2  __attribute__((ext_vector_type(2)));
typedef float    f32x4  __attribute__((ext_vector_type(4)));

static __device__ __forceinline__ float fast_sigmoid(float x) {
    float e = __expf(-x);
    return __builtin_amdgcn_rcpf(1.f + e);
}

// ---------------- K1: prep (blocks 0..4255) ∥ hist (blocks 4256..5279) ----------------
__global__ __launch_bounds__(256) void k_prep_hist(const float* __restrict__ X,
                                                   const float* __restrict__ W1,
                                                   const float* __restrict__ W2,
                                                   const float* __restrict__ W3,
                                                   _Float16* __restrict__ Xh,
                                                   _Float16* __restrict__ W1T,
                                                   _Float16* __restrict__ W23T,
                                                   const int* __restrict__ erow,
                                                   int* __restrict__ counts) {
    int b = blockIdx.x;
    if (b >= 4256) {
        int e = (b - 4256) * 256 + threadIdx.x;
        atomicAdd(&counts[erow[e]], 1);
        return;
    }
    if (b < 4096) {
        // X fp32 -> fp16: 4096 blocks x 256 thr x 4
        int idx = b * 1024 + threadIdx.x * 4;
        float4 x = *(const float4*)&X[idx];
        f16x4 o = {(_Float16)x.x, (_Float16)x.y, (_Float16)x.z, (_Float16)x.w};
        *(f16x4*)&Xh[idx] = o;
        return;
    }
    __shared__ float tile[32][33];
    int c = threadIdx.x & 31;
    int r0 = threadIdx.x >> 5;   // 0..7
    if (b < 4096 + 128) {
        // W1 [512][256] -> W1T [256][512]
        int t = b - 4096;
        int tk = t >> 3;   // 0..15
        int tn = t & 7;    // 0..7
#pragma unroll
        for (int i = 0; i < 4; i++) {
            int r = r0 * 4 + i;
            tile[r][c] = W1[(tk * 32 + r) * HH1 + tn * 32 + c];
        }
        __syncthreads();
#pragma unroll
        for (int i = 0; i < 4; i++) {
            int rr = r0 * 4 + i;
            W1T[(tn * 32 + rr) * IND + tk * 32 + c] = (_Float16)tile[c][rr];
        }
    } else {
        // [W2|W3] [256][64]x2 -> W23T [128][256]
        int t = b - 4224;  // 0..31
        int tk = t >> 2;   // 0..7
        int tn = t & 3;    // tn<2 -> W2, else W3
        const float* Wsrc = (tn < 2) ? W2 : W3;
        int nc0 = (tn & 1) * 32;
#pragma unroll
        for (int i = 0; i < 4; i++) {
            int r = r0 * 4 + i;
            tile[r][c] = Wsrc[(tk * 32 + r) * 64 + nc0 + c];
        }
        __syncthreads();
#pragma unroll
        for (int i = 0; i < 4; i++) {
            int rr = r0 * 4 + i;
            W23T[(tn * 32 + rr) * HH1 + tk * 32 + c] = (_Float16)tile[c][rr];
        }
    }
}

// ---------------- K2: block scan of 8192 counts (256 thr x 32, shfl-based) ----------------
__global__ __launch_bounds__(256) void k_scan256(const int* __restrict__ counts,
                                                 int* __restrict__ row_start,
                                                 int* __restrict__ cursor) {
    __shared__ int wsum[4];
    int t = threadIdx.x;
    int w = t >> 6, l = t & 63;
    int base = t * 32;
    int s = 0;
#pragma unroll
    for (int i = 0; i < 32; i++) s += counts[base + i];
    int inc = s;
    for (int off = 1; off < 64; off <<= 1) {
        int v = __shfl_up(inc, off, 64);
        if (l >= off) inc += v;
    }
    int exc = inc - s;
    if (l == 63) wsum[w] = inc;
    __syncthreads();
    int wpre = 0;
#pragma unroll
    for (int i = 0; i < 4; i++)
        if (i < w) wpre += wsum[i];
    int run = wpre + exc;
#pragma unroll
    for (int i = 0; i < 32; i++) {
        int c = counts[base + i];
        row_start[base + i] = run;
        cursor[base + i] = run;
        run += c;
    }
    if (t == 255) row_start[NN] = run;
}

// ---------------- K3: gemm1 (blocks 0..511) ∥ scatter (blocks 512..1535) ----------------
// gemm1: sup1h = fp16(Xh @ W1T^T). BM=32, BN=128, 4 waves 2x2, per-wave 16x64.
__global__ __launch_bounds__(256) void k_gemm1_scatter(const _Float16* __restrict__ A,
                                                       const _Float16* __restrict__ B,
                                                       _Float16* __restrict__ out,
                                                       const int* __restrict__ erow,
                                                       const int* __restrict__ ecol,
                                                       const float* __restrict__ eval,
                                                       int* __restrict__ cursor,
                                                       int2* __restrict__ epack) {
    int b = blockIdx.x;
    if (b >= 512) {
        int e = (b - 512) * 256 + threadIdx.x;
        int r = erow[e];
        int pos = atomicAdd(&cursor[r], 1);
        epack[pos] = make_int2(ecol[e], __float_as_int(eval[e]));
        return;
    }
    int bm = b >> 1, bn = b & 1;
    int w = threadIdx.x >> 6, l = threadIdx.x & 63;
    int wm = w >> 1, wn = w & 1;
    int lr = l & 15, kg = l >> 4;
    int row0 = bm * 32 + wm * 16;
    int col0 = bn * 128 + wn * 64;

    f32x4 acc[4];
#pragma unroll
    for (int nt = 0; nt < 4; nt++) acc[nt] = (f32x4){0.f, 0.f, 0.f, 0.f};

    for (int ks = 0; ks < IND; ks += 32) {
        int ko = ks + kg * 8;
        f16x8 a = *(const f16x8*)&A[(size_t)(row0 + lr) * IND + ko];
        f16x8 bb[4];
#pragma unroll
        for (int nt = 0; nt < 4; nt++)
            bb[nt] = *(const f16x8*)&B[(size_t)(col0 + nt * 16 + lr) * IND + ko];
#pragma unroll
        for (int nt = 0; nt < 4; nt++)
            acc[nt] = __builtin_amdgcn_mfma_f32_16x16x32_f16(a, bb[nt], acc[nt], 0, 0, 0);
    }
#pragma unroll
    for (int nt = 0; nt < 4; nt++)
#pragma unroll
        for (int r = 0; r < 4; r++)
            out[(size_t)(row0 + kg * 4 + r) * HH1 + col0 + nt * 16 + lr] = (_Float16)acc[nt][r];
}

// ---------------- K4: SpMM1: h = fp16(tanh(A @ sup1h + b1)) ----------------
__global__ __launch_bounds__(256) void k_spmm1v(const int* __restrict__ row_start,
                                                const int2* __restrict__ epack,
                                                const _Float16* __restrict__ sup,
                                                const float* __restrict__ b1,
                                                _Float16* __restrict__ hb) {
    int w = threadIdx.x >> 6, l = threadIdx.x & 63;
    int row = blockIdx.x * 4 + w;
    int s = row_start[row], eend = row_start[row + 1];
    float4 acc = make_float4(0.f, 0.f, 0.f, 0.f);
    int i = s;
    for (; i + 4 <= eend; i += 4) {
        int2 p0 = epack[i];
        int2 p1 = epack[i + 1];
        int2 p2 = epack[i + 2];
        int2 p3 = epack[i + 3];
        f16x4 t0 = *(const f16x4*)&sup[(size_t)p0.x * HH1 + l * 4];
        f16x4 t1 = *(const f16x4*)&sup[(size_t)p1.x * HH1 + l * 4];
        f16x4 t2 = *(const f16x4*)&sup[(size_t)p2.x * HH1 + l * 4];
        f16x4 t3 = *(const f16x4*)&sup[(size_t)p3.x * HH1 + l * 4];
        float v0 = __int_as_float(p0.y), v1 = __int_as_float(p1.y);
        float v2 = __int_as_float(p2.y), v3 = __int_as_float(p3.y);
        acc.x += v0 * (float)t0[0] + v1 * (float)t1[0] + v2 * (float)t2[0] + v3 * (float)t3[0];
        acc.y += v0 * (float)t0[1] + v1 * (float)t1[1] + v2 * (float)t2[1] + v3 * (float)t3[1];
        acc.z += v0 * (float)t0[2] + v1 * (float)t1[2] + v2 * (float)t2[2] + v3 * (float)t3[2];
        acc.w += v0 * (float)t0[3] + v1 * (float)t1[3] + v2 * (float)t2[3] + v3 * (float)t3[3];
    }
    for (; i < eend; i++) {
        int2 p0 = epack[i];
        f16x4 t0 = *(const f16x4*)&sup[(size_t)p0.x * HH1 + l * 4];
        float v0 = __int_as_float(p0.y);
        acc.x += v0 * (float)t0[0];
        acc.y += v0 * (float)t0[1];
        acc.z += v0 * (float)t0[2];
        acc.w += v0 * (float)t0[3];
    }
    float4 bb = ((const float4*)b1)[l];
    f16x4 o;
    o[0] = (_Float16)tanhf(acc.x + bb.x);
    o[1] = (_Float16)tanhf(acc.y + bb.y);
    o[2] = (_Float16)tanhf(acc.z + bb.z);
    o[3] = (_Float16)tanhf(acc.w + bb.w);
    *(f16x4*)&hb[(size_t)row * HH1 + l * 4] = o;
}

// ---------------- K5: GEMM23: s23h = fp16(hb @ W23T^T). BM=16, 4 waves 16x32 ----------------
__global__ __launch_bounds__(256) void k_gemm23_mfma(const _Float16* __restrict__ A,
                                                     const _Float16* __restrict__ B,
                                                     _Float16* __restrict__ out) {
    int bm = blockIdx.x;
    int w = threadIdx.x >> 6, l = threadIdx.x & 63;
    int lr = l & 15, kg = l >> 4;
    int row0 = bm * 16;
    int col0 = w * 32;

    f32x4 acc[2];
#pragma unroll
    for (int nt = 0; nt < 2; nt++) acc[nt] = (f32x4){0.f, 0.f, 0.f, 0.f};

    for (int ks = 0; ks < HH1; ks += 32) {
        int ko = ks + kg * 8;
        f16x8 a = *(const f16x8*)&A[(size_t)(row0 + lr) * HH1 + ko];
        f16x8 bb[2];
#pragma unroll
        for (int nt = 0; nt < 2; nt++)
            bb[nt] = *(const f16x8*)&B[(size_t)(col0 + nt * 16 + lr) * HH1 + ko];
#pragma unroll
        for (int nt = 0; nt < 2; nt++)
            acc[nt] = __builtin_amdgcn_mfma_f32_16x16x32_f16(a, bb[nt], acc[nt], 0, 0, 0);
    }
#pragma unroll
    for (int nt = 0; nt < 2; nt++)
#pragma unroll
        for (int r = 0; r < 4; r++)
            out[(size_t)(row0 + kg * 4 + r) * 128 + col0 + nt * 16 + lr] = (_Float16)acc[nt][r];
}

// ---------------- K6: SpMM2+3 + reparameterization -> zout fp32, zh fp16 ----------------
__global__ __launch_bounds__(256) void k_spmm23v(const int* __restrict__ row_start,
                                                 const int2* __restrict__ epack,
                                                 const _Float16* __restrict__ s23,
                                                 const float* __restrict__ b2,
                                                 const float* __restrict__ b3,
                                                 const float* __restrict__ noise,
                                                 float* __restrict__ zout,
                                                 _Float16* __restrict__ zh) {
    int w = threadIdx.x >> 6, l = threadIdx.x & 63;
    int row = blockIdx.x * 4 + w;
    int s = row_start[row], eend = row_start[row + 1];
    float ax = 0.f, ay = 0.f;
    int i = s;
    for (; i + 4 <= eend; i += 4) {
        int2 p0 = epack[i];
        int2 p1 = epack[i + 1];
        int2 p2 = epack[i + 2];
        int2 p3 = epack[i + 3];
        f16x2 t0 = *(const f16x2*)&s23[(size_t)p0.x * 128 + l * 2];
        f16x2 t1 = *(const f16x2*)&s23[(size_t)p1.x * 128 + l * 2];
        f16x2 t2 = *(const f16x2*)&s23[(size_t)p2.x * 128 + l * 2];
        f16x2 t3 = *(const f16x2*)&s23[(size_t)p3.x * 128 + l * 2];
        float v0 = __int_as_float(p0.y), v1 = __int_as_float(p1.y);
        float v2 = __int_as_float(p2.y), v3 = __int_as_float(p3.y);
        ax += v0 * (float)t0[0] + v1 * (float)t1[0] + v2 * (float)t2[0] + v3 * (float)t3[0];
        ay += v0 * (float)t0[1] + v1 * (float)t1[1] + v2 * (float)t2[1] + v3 * (float)t3[1];
    }
    for (; i < eend; i++) {
        int2 p0 = epack[i];
        f16x2 t0 = *(const f16x2*)&s23[(size_t)p0.x * 128 + l * 2];
        float v0 = __int_as_float(p0.y);
        ax += v0 * (float)t0[0];
        ay += v0 * (float)t0[1];
    }
    float bx, by;
    if (l < 32) { bx = b2[2 * l]; by = b2[2 * l + 1]; }
    else        { bx = b3[2 * (l - 32)]; by = b3[2 * (l - 32) + 1]; }
    float t0 = tanhf(ax + bx);
    float t1 = tanhf(ay + by);
    float u0 = __shfl_xor(t0, 32, 64);   // mean lanes receive log_std partner
    float u1 = __shfl_xor(t1, 32, 64);
    if (l < 32) {
        float2 nz = ((const float2*)noise)[(size_t)row * 32 + l];
        float z0 = t0 + nz.x * __expf(u0);
        float z1 = t1 + nz.y * __expf(u1);
        ((float2*)zout)[(size_t)row * 32 + l] = make_float2(z0, z1);
        *(f16x2*)&zh[(size_t)row * 64 + l * 2] = (f16x2){(_Float16)z0, (_Float16)z1};
    }
}

// ---------------- K7: adj = sigmoid(z @ z^T), MFMA f16, transposed float4 stores ----------------
// adj symmetric: block (bi,bj) computes rows [bi*128+w*32,+32) x cols [bj*128,+128) and writes
// the TRANSPOSE (entry (p,q) written exactly once, by block bi=q/128, bj=p/128).
// Store loop: nt outer, mt inner -> a thread's two 64B halves of the same 128B line are adjacent.
__global__ __launch_bounds__(256) void k_zzt_mfma(const _Float16* __restrict__ zh,
                                                  float* __restrict__ adj) {
    int bi = blockIdx.y, bj = blockIdx.x;
    int tid = threadIdx.x;
    int w = tid >> 6, l = tid & 63;
    int lr = l & 15, kg = l >> 4;
    const int i0 = bi * 128 + w * 32;
    const int j0 = bj * 128;

    f16x8 a[2][2];
#pragma unroll
    for (int mt = 0; mt < 2; mt++)
#pragma unroll
        for (int kk = 0; kk < 2; kk++)
            a[mt][kk] = *(const f16x8*)&zh[(size_t)(i0 + mt * 16 + lr) * 64 + kk * 32 + kg * 8];

    f32x4 acc[2][8];
#pragma unroll
    for (int mt = 0; mt < 2; mt++)
#pragma unroll
        for (int nt = 0; nt < 8; nt++)
            acc[mt][nt] = (f32x4){0.f, 0.f, 0.f, 0.f};

#pragma unroll
    for (int nt = 0; nt < 8; nt++) {
        f16x8 b0 = *(const f16x8*)&zh[(size_t)(j0 + nt * 16 + lr) * 64 + 0  + kg * 8];
        f16x8 b1 = *(const f16x8*)&zh[(size_t)(j0 + nt * 16 + lr) * 64 + 32 + kg * 8];
        acc[0][nt] = __builtin_amdgcn_mfma_f32_16x16x32_f16(a[0][0], b0, acc[0][nt], 0, 0, 0);
        acc[0][nt] = __builtin_amdgcn_mfma_f32_16x16x32_f16(a[0][1], b1, acc[0][nt], 0, 0, 0);
        acc[1][nt] = __builtin_amdgcn_mfma_f32_16x16x32_f16(a[1][0], b0, acc[1][nt], 0, 0, 0);
        acc[1][nt] = __builtin_amdgcn_mfma_f32_16x16x32_f16(a[1][1], b1, acc[1][nt], 0, 0, 0);
    }

#pragma unroll
    for (int nt = 0; nt < 8; nt++) {
#pragma unroll
        for (int mt = 0; mt < 2; mt++) {
            size_t orow = (size_t)(j0 + nt * 16 + lr);
            size_t ocol = (size_t)(i0 + mt * 16 + kg * 4);
            float4 o;
            o.x = fast_sigmoid(acc[mt][nt][0]);
            o.y = fast_sigmoid(acc[mt][nt][1]);
            o.z = fast_sigmoid(acc[mt][nt][2]);
            o.w = fast_sigmoid(acc[mt][nt][3]);
            *(float4*)&adj[orow * NN + ocol] = o;
        }
    }
}

extern "C" void kernel_launch(void* const* d_in, const int* in_sizes, int n_in,
                              void* d_out, int out_size, void* d_ws, size_t ws_size,
                              hipStream_t stream) {
    const int*   erow  = (const int*)d_in[0];
    const int*   ecol  = (const int*)d_in[1];
    const float* eval  = (const float*)d_in[2];
    const float* X     = (const float*)d_in[3];
    const float* W1    = (const float*)d_in[4];
    const float* b1    = (const float*)d_in[5];
    const float* W2    = (const float*)d_in[6];
    const float* b2    = (const float*)d_in[7];
    const float* W3    = (const float*)d_in[8];
    const float* b3    = (const float*)d_in[9];
    const float* noise = (const float*)d_in[10];

    float* adj  = (float*)d_out;
    float* zout = (float*)d_out + (size_t)NN * NN;

    // small scratch in d_ws (~3.5 MB)
    char* ws = (char*)d_ws;
    int*  counts    = (int*)(ws + 0);
    int*  row_start = (int*)(ws + 32768);
    int*  cursor    = (int*)(ws + 69632);
    int2* epack     = (int2*)(ws + 102400);              // 2 MiB
    _Float16* W1T   = (_Float16*)(ws + 2199552);         // 256 KiB
    _Float16* W23T  = (_Float16*)(ws + 2461696);         // 64 KiB
    _Float16* zh    = (_Float16*)(ws + 2527232);         // 1 MiB

    // large temporaries in the adj region of d_out (fully overwritten by k_zzt last)
    char* ob = (char*)d_out;
    _Float16* Xh    = (_Float16*)(ob + 0);               // 8 MiB
    _Float16* sup1h = (_Float16*)(ob + 8388608);         // 4 MiB
    _Float16* hb    = (_Float16*)(ob + 12582912);        // 4 MiB
    _Float16* s23h  = (_Float16*)(ob + 16777216);        // 2 MiB

    hipMemsetAsync(counts, 0, NN * sizeof(int), stream);
    k_prep_hist<<<5280, 256, 0, stream>>>(X, W1, W2, W3, Xh, W1T, W23T, erow, counts);
    k_scan256<<<1, 256, 0, stream>>>(counts, row_start, cursor);
    k_gemm1_scatter<<<1536, 256, 0, stream>>>(Xh, W1T, sup1h, erow, ecol, eval, cursor, epack);
    k_spmm1v<<<NN / 4, 256, 0, stream>>>(row_start, epack, sup1h, b1, hb);
    k_gemm23_mfma<<<512, 256, 0, stream>>>(hb, W23T, s23h);
    k_spmm23v<<<NN / 4, 256, 0, stream>>>(row_start, epack, s23h, b2, b3, noise, zout, zh);
    k_zzt_mfma<<<dim3(64, 64), 256, 0, stream>>>(zh, adj);
}

// Round 8
// 152.935 us; speedup vs baseline: 3.1292x; 1.0997x over previous
//
#include <hip/hip_runtime.h>
#include <math.h>

static constexpr int NN  = 8192;     // nodes
static constexpr int EE  = 262144;   // edges
static constexpr int IND = 512;      // input feature dim
static constexpr int HH1 = 256;
static constexpr int RCAP = 128;     // padded per-row edge capacity (max deg ~56)

typedef _Float16 f16x8  __attribute__((ext_vector_type(8)));
typedef _Float16 f16x4  __attribute__((ext_vector_type(4)));
typedef _Float16 f16x2  __attribute__((ext_vector_type(2)));
typedef float    f32x4  __attribute__((ext_vector_type(4)));

static __device__ __forceinline__ float fast_sigmoid(float x) {
    float e = __expf(-x);
    return __builtin_amdgcn_rcpf(1.f + e);
}

// ---------------- K1: W-prep (blocks 0..159) ∥ padded scatter (blocks 160..1183) ----------------
__global__ __launch_bounds__(256) void k_prepw_scatter(const float* __restrict__ W1,
                                                       const float* __restrict__ W2,
                                                       const float* __restrict__ W3,
                                                       _Float16* __restrict__ W1T,
                                                       _Float16* __restrict__ W23T,
                                                       const int* __restrict__ erow,
                                                       const int* __restrict__ ecol,
                                                       const float* __restrict__ eval,
                                                       int* __restrict__ cnt,
                                                       int2* __restrict__ epack) {
    int b = blockIdx.x;
    if (b >= 160) {
        // direct scatter into padded row segments; no hist/scan needed
        int e = (b - 160) * 256 + threadIdx.x;
        int r = erow[e];
        int pos = atomicAdd(&cnt[r], 1);
        epack[(size_t)r * RCAP + pos] = make_int2(ecol[e], __float_as_int(eval[e]));
        return;
    }
    __shared__ float tile[32][33];
    int c = threadIdx.x & 31;
    int r0 = threadIdx.x >> 5;   // 0..7
    if (b < 128) {
        // W1 [512][256] -> W1T [256][512]
        int tk = b >> 3;   // 0..15
        int tn = b & 7;    // 0..7
#pragma unroll
        for (int i = 0; i < 4; i++) {
            int r = r0 * 4 + i;
            tile[r][c] = W1[(tk * 32 + r) * HH1 + tn * 32 + c];
        }
        __syncthreads();
#pragma unroll
        for (int i = 0; i < 4; i++) {
            int rr = r0 * 4 + i;
            W1T[(tn * 32 + rr) * IND + tk * 32 + c] = (_Float16)tile[c][rr];
        }
    } else {
        // [W2|W3] [256][64]x2 -> W23T [128][256]
        int t = b - 128;   // 0..31
        int tk = t >> 2;   // 0..7
        int tn = t & 3;    // tn<2 -> W2, else W3
        const float* Wsrc = (tn < 2) ? W2 : W3;
        int nc0 = (tn & 1) * 32;
#pragma unroll
        for (int i = 0; i < 4; i++) {
            int r = r0 * 4 + i;
            tile[r][c] = Wsrc[(tk * 32 + r) * 64 + nc0 + c];
        }
        __syncthreads();
#pragma unroll
        for (int i = 0; i < 4; i++) {
            int rr = r0 * 4 + i;
            W23T[(tn * 32 + rr) * HH1 + tk * 32 + c] = (_Float16)tile[c][rr];
        }
    }
}

// ---------------- K2: gemm1: sup1h = fp16(X @ W1); X fp32 converted in-register ----------------
// BM=32, BN=128, grid 512, 4 waves 2x2, per-wave 16x64
__global__ __launch_bounds__(256) void k_gemm1_mfma(const float* __restrict__ X,
                                                    const _Float16* __restrict__ B,
                                                    _Float16* __restrict__ out) {
    int b = blockIdx.x;
    int bm = b >> 1, bn = b & 1;
    int w = threadIdx.x >> 6, l = threadIdx.x & 63;
    int wm = w >> 1, wn = w & 1;
    int lr = l & 15, kg = l >> 4;
    int row0 = bm * 32 + wm * 16;
    int col0 = bn * 128 + wn * 64;

    f32x4 acc[4];
#pragma unroll
    for (int nt = 0; nt < 4; nt++) acc[nt] = (f32x4){0.f, 0.f, 0.f, 0.f};

    for (int ks = 0; ks < IND; ks += 32) {
        int ko = ks + kg * 8;
        const float* xp = &X[(size_t)(row0 + lr) * IND + ko];
        float4 x0 = *(const float4*)xp;
        float4 x1 = *(const float4*)(xp + 4);
        f16x8 a = {(_Float16)x0.x, (_Float16)x0.y, (_Float16)x0.z, (_Float16)x0.w,
                   (_Float16)x1.x, (_Float16)x1.y, (_Float16)x1.z, (_Float16)x1.w};
        f16x8 bb[4];
#pragma unroll
        for (int nt = 0; nt < 4; nt++)
            bb[nt] = *(const f16x8*)&B[(size_t)(col0 + nt * 16 + lr) * IND + ko];
#pragma unroll
        for (int nt = 0; nt < 4; nt++)
            acc[nt] = __builtin_amdgcn_mfma_f32_16x16x32_f16(a, bb[nt], acc[nt], 0, 0, 0);
    }
#pragma unroll
    for (int nt = 0; nt < 4; nt++)
#pragma unroll
        for (int r = 0; r < 4; r++)
            out[(size_t)(row0 + kg * 4 + r) * HH1 + col0 + nt * 16 + lr] = (_Float16)acc[nt][r];
}

// ---------------- K3: SpMM1: h = fp16(tanh(A @ sup1h + b1)), padded CSR ----------------
__global__ __launch_bounds__(256) void k_spmm1v(const int* __restrict__ cnt,
                                                const int2* __restrict__ epack,
                                                const _Float16* __restrict__ sup,
                                                const float* __restrict__ b1,
                                                _Float16* __restrict__ hb) {
    int w = threadIdx.x >> 6, l = threadIdx.x & 63;
    int row = blockIdx.x * 4 + w;
    int s = row * RCAP, eend = s + cnt[row];
    float4 acc = make_float4(0.f, 0.f, 0.f, 0.f);
    int i = s;
    for (; i + 4 <= eend; i += 4) {
        int2 p0 = epack[i];
        int2 p1 = epack[i + 1];
        int2 p2 = epack[i + 2];
        int2 p3 = epack[i + 3];
        f16x4 t0 = *(const f16x4*)&sup[(size_t)p0.x * HH1 + l * 4];
        f16x4 t1 = *(const f16x4*)&sup[(size_t)p1.x * HH1 + l * 4];
        f16x4 t2 = *(const f16x4*)&sup[(size_t)p2.x * HH1 + l * 4];
        f16x4 t3 = *(const f16x4*)&sup[(size_t)p3.x * HH1 + l * 4];
        float v0 = __int_as_float(p0.y), v1 = __int_as_float(p1.y);
        float v2 = __int_as_float(p2.y), v3 = __int_as_float(p3.y);
        acc.x += v0 * (float)t0[0] + v1 * (float)t1[0] + v2 * (float)t2[0] + v3 * (float)t3[0];
        acc.y += v0 * (float)t0[1] + v1 * (float)t1[1] + v2 * (float)t2[1] + v3 * (float)t3[1];
        acc.z += v0 * (float)t0[2] + v1 * (float)t1[2] + v2 * (float)t2[2] + v3 * (float)t3[2];
        acc.w += v0 * (float)t0[3] + v1 * (float)t1[3] + v2 * (float)t2[3] + v3 * (float)t3[3];
    }
    for (; i < eend; i++) {
        int2 p0 = epack[i];
        f16x4 t0 = *(const f16x4*)&sup[(size_t)p0.x * HH1 + l * 4];
        float v0 = __int_as_float(p0.y);
        acc.x += v0 * (float)t0[0];
        acc.y += v0 * (float)t0[1];
        acc.z += v0 * (float)t0[2];
        acc.w += v0 * (float)t0[3];
    }
    float4 bb = ((const float4*)b1)[l];
    f16x4 o;
    o[0] = (_Float16)tanhf(acc.x + bb.x);
    o[1] = (_Float16)tanhf(acc.y + bb.y);
    o[2] = (_Float16)tanhf(acc.z + bb.z);
    o[3] = (_Float16)tanhf(acc.w + bb.w);
    *(f16x4*)&hb[(size_t)row * HH1 + l * 4] = o;
}

// ---------------- K4: GEMM23: s23h = fp16(hb @ W23T^T). BM=16, 4 waves 16x32 ----------------
__global__ __launch_bounds__(256) void k_gemm23_mfma(const _Float16* __restrict__ A,
                                                     const _Float16* __restrict__ B,
                                                     _Float16* __restrict__ out) {
    int bm = blockIdx.x;
    int w = threadIdx.x >> 6, l = threadIdx.x & 63;
    int lr = l & 15, kg = l >> 4;
    int row0 = bm * 16;
    int col0 = w * 32;

    f32x4 acc[2];
#pragma unroll
    for (int nt = 0; nt < 2; nt++) acc[nt] = (f32x4){0.f, 0.f, 0.f, 0.f};

    for (int ks = 0; ks < HH1; ks += 32) {
        int ko = ks + kg * 8;
        f16x8 a = *(const f16x8*)&A[(size_t)(row0 + lr) * HH1 + ko];
        f16x8 bb[2];
#pragma unroll
        for (int nt = 0; nt < 2; nt++)
            bb[nt] = *(const f16x8*)&B[(size_t)(col0 + nt * 16 + lr) * HH1 + ko];
#pragma unroll
        for (int nt = 0; nt < 2; nt++)
            acc[nt] = __builtin_amdgcn_mfma_f32_16x16x32_f16(a, bb[nt], acc[nt], 0, 0, 0);
    }
#pragma unroll
    for (int nt = 0; nt < 2; nt++)
#pragma unroll
        for (int r = 0; r < 4; r++)
            out[(size_t)(row0 + kg * 4 + r) * 128 + col0 + nt * 16 + lr] = (_Float16)acc[nt][r];
}

// ---------------- K5: SpMM2+3 + reparameterization -> zout fp32, zh fp16 ----------------
__global__ __launch_bounds__(256) void k_spmm23v(const int* __restrict__ cnt,
                                                 const int2* __restrict__ epack,
                                                 const _Float16* __restrict__ s23,
                                                 const float* __restrict__ b2,
                                                 const float* __restrict__ b3,
                                                 const float* __restrict__ noise,
                                                 float* __restrict__ zout,
                                                 _Float16* __restrict__ zh) {
    int w = threadIdx.x >> 6, l = threadIdx.x & 63;
    int row = blockIdx.x * 4 + w;
    int s = row * RCAP, eend = s + cnt[row];
    float ax = 0.f, ay = 0.f;
    int i = s;
    for (; i + 4 <= eend; i += 4) {
        int2 p0 = epack[i];
        int2 p1 = epack[i + 1];
        int2 p2 = epack[i + 2];
        int2 p3 = epack[i + 3];
        f16x2 t0 = *(const f16x2*)&s23[(size_t)p0.x * 128 + l * 2];
        f16x2 t1 = *(const f16x2*)&s23[(size_t)p1.x * 128 + l * 2];
        f16x2 t2 = *(const f16x2*)&s23[(size_t)p2.x * 128 + l * 2];
        f16x2 t3 = *(const f16x2*)&s23[(size_t)p3.x * 128 + l * 2];
        float v0 = __int_as_float(p0.y), v1 = __int_as_float(p1.y);
        float v2 = __int_as_float(p2.y), v3 = __int_as_float(p3.y);
        ax += v0 * (float)t0[0] + v1 * (float)t1[0] + v2 * (float)t2[0] + v3 * (float)t3[0];
        ay += v0 * (float)t0[1] + v1 * (float)t1[1] + v2 * (float)t2[1] + v3 * (float)t3[1];
    }
    for (; i < eend; i++) {
        int2 p0 = epack[i];
        f16x2 t0 = *(const f16x2*)&s23[(size_t)p0.x * 128 + l * 2];
        float v0 = __int_as_float(p0.y);
        ax += v0 * (float)t0[0];
        ay += v0 * (float)t0[1];
    }
    float bx, by;
    if (l < 32) { bx = b2[2 * l]; by = b2[2 * l + 1]; }
    else        { bx = b3[2 * (l - 32)]; by = b3[2 * (l - 32) + 1]; }
    float t0 = tanhf(ax + bx);
    float t1 = tanhf(ay + by);
    float u0 = __shfl_xor(t0, 32, 64);   // mean lanes receive log_std partner
    float u1 = __shfl_xor(t1, 32, 64);
    if (l < 32) {
        float2 nz = ((const float2*)noise)[(size_t)row * 32 + l];
        float z0 = t0 + nz.x * __expf(u0);
        float z1 = t1 + nz.y * __expf(u1);
        ((float2*)zout)[(size_t)row * 32 + l] = make_float2(z0, z1);
        *(f16x2*)&zh[(size_t)row * 64 + l * 2] = (f16x2){(_Float16)z0, (_Float16)z1};
    }
}

// ---------------- K6: adj = sigmoid(z @ z^T), MFMA f16, transposed float4 stores ----------------
// adj symmetric: block (bi,bj) computes rows [bi*128+w*32,+32) x cols [bj*128,+128) and writes
// the TRANSPOSE (entry (p,q) written exactly once, by block bi=q/128, bj=p/128).
// Store loop: nt outer, mt inner -> both 64B halves of a 128B line stored adjacently.
__global__ __launch_bounds__(256) void k_zzt_mfma(const _Float16* __restrict__ zh,
                                                  float* __restrict__ adj) {
    int bi = blockIdx.y, bj = blockIdx.x;
    int tid = threadIdx.x;
    int w = tid >> 6, l = tid & 63;
    int lr = l & 15, kg = l >> 4;
    const int i0 = bi * 128 + w * 32;
    const int j0 = bj * 128;

    f16x8 a[2][2];
#pragma unroll
    for (int mt = 0; mt < 2; mt++)
#pragma unroll
        for (int kk = 0; kk < 2; kk++)
            a[mt][kk] = *(const f16x8*)&zh[(size_t)(i0 + mt * 16 + lr) * 64 + kk * 32 + kg * 8];

    f32x4 acc[2][8];
#pragma unroll
    for (int mt = 0; mt < 2; mt++)
#pragma unroll
        for (int nt = 0; nt < 8; nt++)
            acc[mt][nt] = (f32x4){0.f, 0.f, 0.f, 0.f};

#pragma unroll
    for (int nt = 0; nt < 8; nt++) {
        f16x8 b0 = *(const f16x8*)&zh[(size_t)(j0 + nt * 16 + lr) * 64 + 0  + kg * 8];
        f16x8 b1 = *(const f16x8*)&zh[(size_t)(j0 + nt * 16 + lr) * 64 + 32 + kg * 8];
        acc[0][nt] = __builtin_amdgcn_mfma_f32_16x16x32_f16(a[0][0], b0, acc[0][nt], 0, 0, 0);
        acc[0][nt] = __builtin_amdgcn_mfma_f32_16x16x32_f16(a[0][1], b1, acc[0][nt], 0, 0, 0);
        acc[1][nt] = __builtin_amdgcn_mfma_f32_16x16x32_f16(a[1][0], b0, acc[1][nt], 0, 0, 0);
        acc[1][nt] = __builtin_amdgcn_mfma_f32_16x16x32_f16(a[1][1], b1, acc[1][nt], 0, 0, 0);
    }

#pragma unroll
    for (int nt = 0; nt < 8; nt++) {
#pragma unroll
        for (int mt = 0; mt < 2; mt++) {
            size_t orow = (size_t)(j0 + nt * 16 + lr);
            size_t ocol = (size_t)(i0 + mt * 16 + kg * 4);
            float4 o;
            o.x = fast_sigmoid(acc[mt][nt][0]);
            o.y = fast_sigmoid(acc[mt][nt][1]);
            o.z = fast_sigmoid(acc[mt][nt][2]);
            o.w = fast_sigmoid(acc[mt][nt][3]);
            *(float4*)&adj[orow * NN + ocol] = o;
        }
    }
}

extern "C" void kernel_launch(void* const* d_in, const int* in_sizes, int n_in,
                              void* d_out, int out_size, void* d_ws, size_t ws_size,
                              hipStream_t stream) {
    const int*   erow  = (const int*)d_in[0];
    const int*   ecol  = (const int*)d_in[1];
    const float* eval  = (const float*)d_in[2];
    const float* X     = (const float*)d_in[3];
    const float* W1    = (const float*)d_in[4];
    const float* b1    = (const float*)d_in[5];
    const float* W2    = (const float*)d_in[6];
    const float* b2    = (const float*)d_in[7];
    const float* W3    = (const float*)d_in[8];
    const float* b3    = (const float*)d_in[9];
    const float* noise = (const float*)d_in[10];

    float* adj  = (float*)d_out;
    float* zout = (float*)d_out + (size_t)NN * NN;

    // scratch in d_ws (~9.5 MB; 23 MB proven safe in R1)
    char* ws = (char*)d_ws;
    int*  cnt       = (int*)(ws + 0);                    // 32 KiB
    int2* epack     = (int2*)(ws + 32768);               // 8192*128*8 = 8 MiB (padded rows)
    _Float16* W1T   = (_Float16*)(ws + 8421376);         // 256 KiB
    _Float16* W23T  = (_Float16*)(ws + 8683520);         // 64 KiB
    _Float16* zh    = (_Float16*)(ws + 8749056);         // 1 MiB

    // large temporaries in the adj region of d_out (fully overwritten by k_zzt last)
    char* ob = (char*)d_out;
    _Float16* sup1h = (_Float16*)(ob + 0);               // 4 MiB
    _Float16* hb    = (_Float16*)(ob + 4194304);         // 4 MiB
    _Float16* s23h  = (_Float16*)(ob + 8388608);         // 2 MiB

    hipMemsetAsync(cnt, 0, NN * sizeof(int), stream);
    k_prepw_scatter<<<160 + EE / 256, 256, 0, stream>>>(W1, W2, W3, W1T, W23T,
                                                        erow, ecol, eval, cnt, epack);
    k_gemm1_mfma<<<512, 256, 0, stream>>>(X, W1T, sup1h);
    k_spmm1v<<<NN / 4, 256, 0, stream>>>(cnt, epack, sup1h, b1, hb);
    k_gemm23_mfma<<<512, 256, 0, stream>>>(hb, W23T, s23h);
    k_spmm23v<<<NN / 4, 256, 0, stream>>>(cnt, epack, s23h, b2, b3, noise, zout, zh);
    k_zzt_mfma<<<dim3(64, 64), 256, 0, stream>>>(zh, adj);
}

// Round 9
// 141.681 us; speedup vs baseline: 3.3778x; 1.0794x over previous
//
#include <hip/hip_runtime.h>
#include <math.h>

static constexpr int NN  = 8192;     // nodes
static constexpr int EE  = 262144;   // edges
static constexpr int IND = 512;      // input feature dim
static constexpr int HH1 = 256;
static constexpr int RCAP = 128;     // padded per-row edge capacity (max deg ~56)

typedef _Float16 f16x8  __attribute__((ext_vector_type(8)));
typedef _Float16 f16x4  __attribute__((ext_vector_type(4)));
typedef _Float16 f16x2  __attribute__((ext_vector_type(2)));
typedef float    f32x4  __attribute__((ext_vector_type(4)));

static __device__ __forceinline__ float fast_sigmoid(float x) {
    float e = __expf(-x);
    return __builtin_amdgcn_rcpf(1.f + e);
}

// ---------------- K0: init = zero cnt (blocks 0..31) + W1T (32..159) + W23T (160..191) ----------
__global__ __launch_bounds__(256) void k_init(const float* __restrict__ W1,
                                              const float* __restrict__ W2,
                                              const float* __restrict__ W3,
                                              _Float16* __restrict__ W1T,
                                              _Float16* __restrict__ W23T,
                                              int* __restrict__ cnt) {
    int b = blockIdx.x;
    if (b < 32) {
        cnt[b * 256 + threadIdx.x] = 0;
        return;
    }
    __shared__ float tile[32][33];
    int c = threadIdx.x & 31;
    int r0 = threadIdx.x >> 5;   // 0..7
    if (b < 160) {
        // W1 [512][256] -> W1T [256][512]
        int t = b - 32;
        int tk = t >> 3;   // 0..15
        int tn = t & 7;    // 0..7
#pragma unroll
        for (int i = 0; i < 4; i++) {
            int r = r0 * 4 + i;
            tile[r][c] = W1[(tk * 32 + r) * HH1 + tn * 32 + c];
        }
        __syncthreads();
#pragma unroll
        for (int i = 0; i < 4; i++) {
            int rr = r0 * 4 + i;
            W1T[(tn * 32 + rr) * IND + tk * 32 + c] = (_Float16)tile[c][rr];
        }
    } else {
        // [W2|W3] [256][64]x2 -> W23T [128][256]
        int t = b - 160;   // 0..31
        int tk = t >> 2;   // 0..7
        int tn = t & 3;    // tn<2 -> W2, else W3
        const float* Wsrc = (tn < 2) ? W2 : W3;
        int nc0 = (tn & 1) * 32;
#pragma unroll
        for (int i = 0; i < 4; i++) {
            int r = r0 * 4 + i;
            tile[r][c] = Wsrc[(tk * 32 + r) * 64 + nc0 + c];
        }
        __syncthreads();
#pragma unroll
        for (int i = 0; i < 4; i++) {
            int rr = r0 * 4 + i;
            W23T[(tn * 32 + rr) * HH1 + tk * 32 + c] = (_Float16)tile[c][rr];
        }
    }
}

// ---------------- K1: gemm1 (blocks 0..511) ∥ padded scatter (blocks 512..1535) ----------------
// gemm1: sup1h = fp16(X @ W1); X fp32 converted in-register. BM=32, BN=128, 4 waves 2x2.
__global__ __launch_bounds__(256) void k_gemm1_scatter(const float* __restrict__ X,
                                                       const _Float16* __restrict__ B,
                                                       _Float16* __restrict__ out,
                                                       const int* __restrict__ erow,
                                                       const int* __restrict__ ecol,
                                                       const float* __restrict__ eval,
                                                       int* __restrict__ cnt,
                                                       int2* __restrict__ epack) {
    int b = blockIdx.x;
    if (b >= 512) {
        int e = (b - 512) * 256 + threadIdx.x;
        int r = erow[e];
        int pos = atomicAdd(&cnt[r], 1);
        epack[(size_t)r * RCAP + pos] = make_int2(ecol[e], __float_as_int(eval[e]));
        return;
    }
    int bm = b >> 1, bn = b & 1;
    int w = threadIdx.x >> 6, l = threadIdx.x & 63;
    int wm = w >> 1, wn = w & 1;
    int lr = l & 15, kg = l >> 4;
    int row0 = bm * 32 + wm * 16;
    int col0 = bn * 128 + wn * 64;

    f32x4 acc[4];
#pragma unroll
    for (int nt = 0; nt < 4; nt++) acc[nt] = (f32x4){0.f, 0.f, 0.f, 0.f};

    for (int ks = 0; ks < IND; ks += 32) {
        int ko = ks + kg * 8;
        const float* xp = &X[(size_t)(row0 + lr) * IND + ko];
        float4 x0 = *(const float4*)xp;
        float4 x1 = *(const float4*)(xp + 4);
        f16x8 a = {(_Float16)x0.x, (_Float16)x0.y, (_Float16)x0.z, (_Float16)x0.w,
                   (_Float16)x1.x, (_Float16)x1.y, (_Float16)x1.z, (_Float16)x1.w};
        f16x8 bb[4];
#pragma unroll
        for (int nt = 0; nt < 4; nt++)
            bb[nt] = *(const f16x8*)&B[(size_t)(col0 + nt * 16 + lr) * IND + ko];
#pragma unroll
        for (int nt = 0; nt < 4; nt++)
            acc[nt] = __builtin_amdgcn_mfma_f32_16x16x32_f16(a, bb[nt], acc[nt], 0, 0, 0);
    }
#pragma unroll
    for (int nt = 0; nt < 4; nt++)
#pragma unroll
        for (int r = 0; r < 4; r++)
            out[(size_t)(row0 + kg * 4 + r) * HH1 + col0 + nt * 16 + lr] = (_Float16)acc[nt][r];
}

// ---------------- K2: fused SpMM1 + GEMM23: s23h = fp16( tanh(A@sup1h + b1) @ [W2|W3] ) -------
// 512 blocks x 512 threads (8 waves). Wave w aggregates rows 2w, 2w+1 (gather at full
// occupancy), tanh result staged in LDS [16][264] fp16 (pad: 528B stride = 4-bank offset),
// then each wave does 8 MFMAs for a 16-col slice of s23. h never touches global memory.
__global__ __launch_bounds__(512) void k_spmm1_gemm23(const int* __restrict__ cnt,
                                                      const int2* __restrict__ epack,
                                                      const _Float16* __restrict__ sup,
                                                      const float* __restrict__ b1,
                                                      const _Float16* __restrict__ W23T,
                                                      _Float16* __restrict__ s23h) {
    __shared__ _Float16 hs[16][264];
    int w = threadIdx.x >> 6, l = threadIdx.x & 63;
    int brow0 = blockIdx.x * 16;

#pragma unroll
    for (int rr = 0; rr < 2; rr++) {
        int rloc = w * 2 + rr;
        int row = brow0 + rloc;
        int s = row * RCAP, eend = s + cnt[row];
        float4 acc = make_float4(0.f, 0.f, 0.f, 0.f);
        int i = s;
        for (; i + 4 <= eend; i += 4) {
            int2 p0 = epack[i];
            int2 p1 = epack[i + 1];
            int2 p2 = epack[i + 2];
            int2 p3 = epack[i + 3];
            f16x4 t0 = *(const f16x4*)&sup[(size_t)p0.x * HH1 + l * 4];
            f16x4 t1 = *(const f16x4*)&sup[(size_t)p1.x * HH1 + l * 4];
            f16x4 t2 = *(const f16x4*)&sup[(size_t)p2.x * HH1 + l * 4];
            f16x4 t3 = *(const f16x4*)&sup[(size_t)p3.x * HH1 + l * 4];
            float v0 = __int_as_float(p0.y), v1 = __int_as_float(p1.y);
            float v2 = __int_as_float(p2.y), v3 = __int_as_float(p3.y);
            acc.x += v0 * (float)t0[0] + v1 * (float)t1[0] + v2 * (float)t2[0] + v3 * (float)t3[0];
            acc.y += v0 * (float)t0[1] + v1 * (float)t1[1] + v2 * (float)t2[1] + v3 * (float)t3[1];
            acc.z += v0 * (float)t0[2] + v1 * (float)t1[2] + v2 * (float)t2[2] + v3 * (float)t3[2];
            acc.w += v0 * (float)t0[3] + v1 * (float)t1[3] + v2 * (float)t2[3] + v3 * (float)t3[3];
        }
        for (; i < eend; i++) {
            int2 p0 = epack[i];
            f16x4 t0 = *(const f16x4*)&sup[(size_t)p0.x * HH1 + l * 4];
            float v0 = __int_as_float(p0.y);
            acc.x += v0 * (float)t0[0];
            acc.y += v0 * (float)t0[1];
            acc.z += v0 * (float)t0[2];
            acc.w += v0 * (float)t0[3];
        }
        float4 bb = ((const float4*)b1)[l];
        f16x4 o;
        o[0] = (_Float16)tanhf(acc.x + bb.x);
        o[1] = (_Float16)tanhf(acc.y + bb.y);
        o[2] = (_Float16)tanhf(acc.z + bb.z);
        o[3] = (_Float16)tanhf(acc.w + bb.w);
        *(f16x4*)&hs[rloc][l * 4] = o;
    }
    __syncthreads();

    // GEMM23 phase: wave w -> s23 cols [16w, 16w+16), rows [brow0, brow0+16)
    int lr = l & 15, kg = l >> 4;
    int colbase = w * 16;
    f32x4 acc = (f32x4){0.f, 0.f, 0.f, 0.f};
    for (int ks = 0; ks < HH1; ks += 32) {
        int ko = ks + kg * 8;
        f16x8 a = *(const f16x8*)&hs[lr][ko];
        f16x8 bfrag = *(const f16x8*)&W23T[(size_t)(colbase + lr) * HH1 + ko];
        acc = __builtin_amdgcn_mfma_f32_16x16x32_f16(a, bfrag, acc, 0, 0, 0);
    }
#pragma unroll
    for (int r = 0; r < 4; r++)
        s23h[(size_t)(brow0 + kg * 4 + r) * 128 + colbase + lr] = (_Float16)acc[r];
}

// ---------------- K3: SpMM2+3 + reparameterization -> zout fp32, zh fp16 ----------------
__global__ __launch_bounds__(256) void k_spmm23v(const int* __restrict__ cnt,
                                                 const int2* __restrict__ epack,
                                                 const _Float16* __restrict__ s23,
                                                 const float* __restrict__ b2,
                                                 const float* __restrict__ b3,
                                                 const float* __restrict__ noise,
                                                 float* __restrict__ zout,
                                                 _Float16* __restrict__ zh) {
    int w = threadIdx.x >> 6, l = threadIdx.x & 63;
    int row = blockIdx.x * 4 + w;
    int s = row * RCAP, eend = s + cnt[row];
    float ax = 0.f, ay = 0.f;
    int i = s;
    for (; i + 4 <= eend; i += 4) {
        int2 p0 = epack[i];
        int2 p1 = epack[i + 1];
        int2 p2 = epack[i + 2];
        int2 p3 = epack[i + 3];
        f16x2 t0 = *(const f16x2*)&s23[(size_t)p0.x * 128 + l * 2];
        f16x2 t1 = *(const f16x2*)&s23[(size_t)p1.x * 128 + l * 2];
        f16x2 t2 = *(const f16x2*)&s23[(size_t)p2.x * 128 + l * 2];
        f16x2 t3 = *(const f16x2*)&s23[(size_t)p3.x * 128 + l * 2];
        float v0 = __int_as_float(p0.y), v1 = __int_as_float(p1.y);
        float v2 = __int_as_float(p2.y), v3 = __int_as_float(p3.y);
        ax += v0 * (float)t0[0] + v1 * (float)t1[0] + v2 * (float)t2[0] + v3 * (float)t3[0];
        ay += v0 * (float)t0[1] + v1 * (float)t1[1] + v2 * (float)t2[1] + v3 * (float)t3[1];
    }
    for (; i < eend; i++) {
        int2 p0 = epack[i];
        f16x2 t0 = *(const f16x2*)&s23[(size_t)p0.x * 128 + l * 2];
        float v0 = __int_as_float(p0.y);
        ax += v0 * (float)t0[0];
        ay += v0 * (float)t0[1];
    }
    float bx, by;
    if (l < 32) { bx = b2[2 * l]; by = b2[2 * l + 1]; }
    else        { bx = b3[2 * (l - 32)]; by = b3[2 * (l - 32) + 1]; }
    float t0 = tanhf(ax + bx);
    float t1 = tanhf(ay + by);
    float u0 = __shfl_xor(t0, 32, 64);   // mean lanes receive log_std partner
    float u1 = __shfl_xor(t1, 32, 64);
    if (l < 32) {
        float2 nz = ((const float2*)noise)[(size_t)row * 32 + l];
        float z0 = t0 + nz.x * __expf(u0);
        float z1 = t1 + nz.y * __expf(u1);
        ((float2*)zout)[(size_t)row * 32 + l] = make_float2(z0, z1);
        *(f16x2*)&zh[(size_t)row * 64 + l * 2] = (f16x2){(_Float16)z0, (_Float16)z1};
    }
}

// ---------------- K4: adj = sigmoid(z @ z^T), MFMA f16, transposed float4 stores ----------------
// adj symmetric: block (bi,bj) computes rows [bi*128+w*32,+32) x cols [bj*128,+128) and writes
// the TRANSPOSE (entry (p,q) written exactly once, by block bi=q/128, bj=p/128).
__global__ __launch_bounds__(256) void k_zzt_mfma(const _Float16* __restrict__ zh,
                                                  float* __restrict__ adj) {
    int bi = blockIdx.y, bj = blockIdx.x;
    int tid = threadIdx.x;
    int w = tid >> 6, l = tid & 63;
    int lr = l & 15, kg = l >> 4;
    const int i0 = bi * 128 + w * 32;
    const int j0 = bj * 128;

    f16x8 a[2][2];
#pragma unroll
    for (int mt = 0; mt < 2; mt++)
#pragma unroll
        for (int kk = 0; kk < 2; kk++)
            a[mt][kk] = *(const f16x8*)&zh[(size_t)(i0 + mt * 16 + lr) * 64 + kk * 32 + kg * 8];

    f32x4 acc[2][8];
#pragma unroll
    for (int mt = 0; mt < 2; mt++)
#pragma unroll
        for (int nt = 0; nt < 8; nt++)
            acc[mt][nt] = (f32x4){0.f, 0.f, 0.f, 0.f};

#pragma unroll
    for (int nt = 0; nt < 8; nt++) {
        f16x8 b0 = *(const f16x8*)&zh[(size_t)(j0 + nt * 16 + lr) * 64 + 0  + kg * 8];
        f16x8 b1 = *(const f16x8*)&zh[(size_t)(j0 + nt * 16 + lr) * 64 + 32 + kg * 8];
        acc[0][nt] = __builtin_amdgcn_mfma_f32_16x16x32_f16(a[0][0], b0, acc[0][nt], 0, 0, 0);
        acc[0][nt] = __builtin_amdgcn_mfma_f32_16x16x32_f16(a[0][1], b1, acc[0][nt], 0, 0, 0);
        acc[1][nt] = __builtin_amdgcn_mfma_f32_16x16x32_f16(a[1][0], b0, acc[1][nt], 0, 0, 0);
        acc[1][nt] = __builtin_amdgcn_mfma_f32_16x16x32_f16(a[1][1], b1, acc[1][nt], 0, 0, 0);
    }

#pragma unroll
    for (int nt = 0; nt < 8; nt++) {
#pragma unroll
        for (int mt = 0; mt < 2; mt++) {
            size_t orow = (size_t)(j0 + nt * 16 + lr);
            size_t ocol = (size_t)(i0 + mt * 16 + kg * 4);
            float4 o;
            o.x = fast_sigmoid(acc[mt][nt][0]);
            o.y = fast_sigmoid(acc[mt][nt][1]);
            o.z = fast_sigmoid(acc[mt][nt][2]);
            o.w = fast_sigmoid(acc[mt][nt][3]);
            *(float4*)&adj[orow * NN + ocol] = o;
        }
    }
}

extern "C" void kernel_launch(void* const* d_in, const int* in_sizes, int n_in,
                              void* d_out, int out_size, void* d_ws, size_t ws_size,
                              hipStream_t stream) {
    const int*   erow  = (const int*)d_in[0];
    const int*   ecol  = (const int*)d_in[1];
    const float* eval  = (const float*)d_in[2];
    const float* X     = (const float*)d_in[3];
    const float* W1    = (const float*)d_in[4];
    const float* b1    = (const float*)d_in[5];
    const float* W2    = (const float*)d_in[6];
    const float* b2    = (const float*)d_in[7];
    const float* W3    = (const float*)d_in[8];
    const float* b3    = (const float*)d_in[9];
    const float* noise = (const float*)d_in[10];

    float* adj  = (float*)d_out;
    float* zout = (float*)d_out + (size_t)NN * NN;

    // scratch in d_ws (~9.8 MB)
    char* ws = (char*)d_ws;
    int*  cnt       = (int*)(ws + 0);                    // 32 KiB
    int2* epack     = (int2*)(ws + 32768);               // 8 MiB (padded rows)
    _Float16* W1T   = (_Float16*)(ws + 8421376);         // 256 KiB
    _Float16* W23T  = (_Float16*)(ws + 8683520);         // 64 KiB
    _Float16* zh    = (_Float16*)(ws + 8749056);         // 1 MiB

    // large temporaries in the adj region of d_out (fully overwritten by k_zzt last)
    char* ob = (char*)d_out;
    _Float16* sup1h = (_Float16*)(ob + 0);               // 4 MiB
    _Float16* s23h  = (_Float16*)(ob + 4194304);         // 2 MiB

    k_init<<<192, 256, 0, stream>>>(W1, W2, W3, W1T, W23T, cnt);
    k_gemm1_scatter<<<512 + EE / 256, 256, 0, stream>>>(X, W1T, sup1h,
                                                        erow, ecol, eval, cnt, epack);
    k_spmm1_gemm23<<<512, 512, 0, stream>>>(cnt, epack, sup1h, b1, W23T, s23h);
    k_spmm23v<<<NN / 4, 256, 0, stream>>>(cnt, epack, s23h, b2, b3, noise, zout, zh);
    k_zzt_mfma<<<dim3(64, 64), 256, 0, stream>>>(zh, adj);
}